// Round 1
// baseline (22122.855 us; speedup 1.0000x reference)
//
#include <hip/hip_runtime.h>

typedef unsigned short u16;
typedef __attribute__((ext_vector_type(8))) short bf16x8;
typedef __attribute__((ext_vector_type(8))) unsigned short u16x8;
typedef __attribute__((ext_vector_type(4))) float f32x4;

#define DEVI static __device__ __forceinline__

constexpr int B = 32, S = 128, T = 64, H = 512, V = 32000;
constexpr int H4 = 4 * H;          // 2048
constexpr int TD = T - 1;          // 63 decoder steps
constexpr int MOUT = TD * B;       // 2016
constexpr int KOUT = 3 * H;        // 1536
constexpr int PAD_IDX = 1;

DEVI u16 f2bf(float f) {
  union { float f; unsigned u; } v; v.f = f;
  unsigned r = (v.u + 0x7fffu + ((v.u >> 16) & 1u)) >> 16;
  return (u16)r;
}
DEVI float sigm(float x) { return 1.f / (1.f + __expf(-x)); }
DEVI float tanh_(float x) {
  float ax = fabsf(x);
  float e = __expf(-2.f * ax);
  float t = (1.f - e) / (1.f + e);
  return x < 0.f ? -t : t;
}
DEVI float dot4(float4 a, float4 b) {
  return a.x * b.x + a.y * b.y + a.z * b.z + a.w * b.w;
}
DEVI int swz(int row, int k8) { return row * 32 + ((k8 ^ (row & 3)) << 3); }

// ---------------- bf16 MFMA GEMM:  C[M,N] = A[M,K] * Bt[N,K]^T + bias ------
// A, Bt bf16 row-major (K contiguous); C fp32. N multiple of 128, K mult of 32.
// M guarded. 128x128 tile, 4 waves, 64x64/wave, 16x16x32 MFMA, XOR-swizzled LDS.
__global__ __launch_bounds__(256) void gemm_bt(
    const u16* __restrict__ A, int lda,
    const u16* __restrict__ Bt, int ldb,
    float* __restrict__ C, int ldc,
    const float* __restrict__ bias, int M, int K) {
  __shared__ u16 As[128 * 32], Bs[128 * 32];
  const int tid = threadIdx.x;
  const int m0 = blockIdx.y * 128, n0 = blockIdx.x * 128;
  const int lane = tid & 63, w = tid >> 6, wm = w >> 1, wn = w & 1;
  const int lr = lane & 15, lk = lane >> 4;
  f32x4 acc[4][4] = {};
  const int r = tid >> 1, cc = (tid & 1) * 16, k8b = (tid & 1) * 2;

  for (int k0 = 0; k0 < K; k0 += 32) {
    {  // stage A (guard M rows)
      long gr = m0 + r;
      u16x8 v0 = {}, v1 = {};
      if (gr < M) {
        const u16* s = A + gr * (long)lda + k0 + cc;
        v0 = *(const u16x8*)s;
        v1 = *(const u16x8*)(s + 8);
      }
      *(u16x8*)&As[swz(r, k8b)] = v0;
      *(u16x8*)&As[swz(r, k8b + 1)] = v1;
    }
    {  // stage B (N always multiple of 128)
      const u16* s = Bt + (long)(n0 + r) * ldb + k0 + cc;
      u16x8 v0 = *(const u16x8*)s;
      u16x8 v1 = *(const u16x8*)(s + 8);
      *(u16x8*)&Bs[swz(r, k8b)] = v0;
      *(u16x8*)&Bs[swz(r, k8b + 1)] = v1;
    }
    __syncthreads();
    bf16x8 af[4], bfr[4];
#pragma unroll
    for (int mi = 0; mi < 4; mi++)
      af[mi] = *(const bf16x8*)&As[swz(wm * 64 + mi * 16 + lr, lk)];
#pragma unroll
    for (int ni = 0; ni < 4; ni++)
      bfr[ni] = *(const bf16x8*)&Bs[swz(wn * 64 + ni * 16 + lr, lk)];
#pragma unroll
    for (int mi = 0; mi < 4; mi++)
#pragma unroll
      for (int ni = 0; ni < 4; ni++)
        acc[mi][ni] = __builtin_amdgcn_mfma_f32_16x16x32_bf16(
            af[mi], bfr[ni], acc[mi][ni], 0, 0, 0);
    __syncthreads();
  }
#pragma unroll
  for (int ni = 0; ni < 4; ni++) {
    int col = n0 + wn * 64 + ni * 16 + lr;
    float bs = bias ? bias[col] : 0.f;
#pragma unroll
    for (int mi = 0; mi < 4; mi++) {
#pragma unroll
      for (int rr = 0; rr < 4; rr++) {
        long row = m0 + wm * 64 + mi * 16 + lk * 4 + rr;
        if (row < M) C[row * (long)ldc + col] = acc[mi][ni][rr] + bs;
      }
    }
  }
}

// ---------------- elementwise helpers --------------------------------------
__global__ void zero_f(float* p, long n) {
  long i = (long)blockIdx.x * 256 + threadIdx.x;
  long st = (long)gridDim.x * 256;
  for (; i < n; i += st) p[i] = 0.f;
}

__global__ void cast_bf(const float* __restrict__ src, u16* __restrict__ dst,
                        int ld, int off, int Csz) {
  long row = blockIdx.y;
  int col = blockIdx.x * 256 + threadIdx.x;
  dst[row * Csz + col] = f2bf(src[row * ld + off + col]);
}

__global__ void bias_sum(const float* __restrict__ a,
                         const float* __restrict__ b, float* __restrict__ o) {
  int i = blockIdx.x * 256 + threadIdx.x;
  o[i] = a[i] + b[i];
}

__global__ void gather_src_emb(const int* __restrict__ src,
                               const float* __restrict__ emb,
                               u16* __restrict__ dst) {
  int row = blockIdx.y;           // row = t*B + b
  int t = row >> 5, b = row & 31; // B == 32
  int c = blockIdx.x * 256 + threadIdx.x;
  int tok = src[b * S + t];
  dst[(long)row * H + c] = f2bf(emb[(long)tok * H + c]);
}

__global__ void gather_trg_emb(const int* __restrict__ trg,
                               const float* __restrict__ emb,
                               u16* __restrict__ xout) {
  int row = blockIdx.y;           // row = t*B + b, t < 63
  int t = row >> 5, b = row & 31;
  int c = blockIdx.x * 256 + threadIdx.x;
  int tok = trg[b * T + t];
  xout[(long)row * KOUT + 2 * H + c] = f2bf(emb[(long)tok * H + c]);
}

// ---------------- encoder LSTM step ----------------------------------------
__global__ __launch_bounds__(256) void lstm_enc_step(
    const float* __restrict__ xih,  // [B,H4] this step (bih+bhh folded)
    const float* __restrict__ whh,  // [H4,H]
    const float* __restrict__ h_in, float* __restrict__ h_out,
    float* __restrict__ c,
    float* __restrict__ enc_bt, u16* __restrict__ enc_bt_bf, int t) {
  __shared__ float hs[H];
  int tid = threadIdx.x;
  int b = blockIdx.x >> 1, half = blockIdx.x & 1, j = half * 256 + tid;
  hs[tid] = h_in[b * H + tid];
  hs[tid + 256] = h_in[b * H + 256 + tid];
  __syncthreads();
  const float4* hv = (const float4*)hs;
  const float4* w0 = (const float4*)(whh + (long)j * H);
  const float4* w1 = (const float4*)(whh + (long)(H + j) * H);
  const float4* w2 = (const float4*)(whh + (long)(2 * H + j) * H);
  const float4* w3 = (const float4*)(whh + (long)(3 * H + j) * H);
  float a0 = 0, a1 = 0, a2 = 0, a3 = 0;
#pragma unroll 4
  for (int k = 0; k < H / 4; k++) {
    float4 h4 = hv[k];
    a0 += dot4(h4, w0[k]);
    a1 += dot4(h4, w1[k]);
    a2 += dot4(h4, w2[k]);
    a3 += dot4(h4, w3[k]);
  }
  long xb = (long)b * H4;
  float gi = xih[xb + j] + a0;
  float gf = xih[xb + H + j] + a1;
  float gg = xih[xb + 2 * H + j] + a2;
  float go = xih[xb + 3 * H + j] + a3;
  float cn = sigm(gf) * c[b * H + j] + sigm(gi) * tanh_(gg);
  c[b * H + j] = cn;
  float hn = sigm(go) * tanh_(cn);
  h_out[b * H + j] = hn;
  long ei = ((long)b * S + t) * H + j;
  enc_bt[ei] = hn;
  enc_bt_bf[ei] = f2bf(hn);
}

// ---------------- hidden = tanh(hf @ fc_w^T + fc_b) ------------------------
__global__ __launch_bounds__(256) void fc_tanh(
    const float* __restrict__ hf, const float* __restrict__ w,
    const float* __restrict__ bias, float* __restrict__ hout) {
  __shared__ float hs[H];
  int tid = threadIdx.x;
  int b = blockIdx.x >> 1, half = blockIdx.x & 1, j = half * 256 + tid;
  hs[tid] = hf[b * H + tid];
  hs[tid + 256] = hf[b * H + 256 + tid];
  __syncthreads();
  const float4* hv = (const float4*)hs;
  const float4* wr = (const float4*)(w + (long)j * H);
  float a = 0;
#pragma unroll 4
  for (int k = 0; k < H / 4; k++) a += dot4(hv[k], wr[k]);
  hout[b * H + j] = tanh_(a + bias[j]);
}

// ---------------- attention step (one block per batch row) -----------------
__global__ __launch_bounds__(256) void attn_step(
    const float* __restrict__ h_in,
    const float* __restrict__ attn_w,  // [H, 2H], cols 0..H-1 = h part
    const float* __restrict__ attn_v,
    const float* __restrict__ epart,   // [B*S, H]  (enc@W2^T + b)
    const float* __restrict__ enc_bt,  // [B*S, H] fp32
    const int* __restrict__ src,
    float* __restrict__ weighted, u16* __restrict__ xout, int t) {
  __shared__ float hs[H], hp[H], av[H], sc[S], part[256], red[1];
  int tid = threadIdx.x, b = blockIdx.x;
  hs[tid] = h_in[b * H + tid];
  hs[tid + 256] = h_in[b * H + 256 + tid];
  av[tid] = attn_v[tid];
  av[tid + 256] = attn_v[tid + 256];
  __syncthreads();
  const float4* hv = (const float4*)hs;
#pragma unroll
  for (int rep = 0; rep < 2; rep++) {  // hpart = h @ W1^T
    int j = tid + rep * 256;
    const float4* wr = (const float4*)(attn_w + (long)j * (2 * H));
    float a = 0;
#pragma unroll 4
    for (int k = 0; k < H / 4; k++) a += dot4(hv[k], wr[k]);
    hp[j] = a;
  }
  __syncthreads();
  {  // scores: 2 threads per s
    int s = tid & (S - 1), jh = tid >> 7;
    const float* ep = epart + ((long)b * S + s) * H + jh * 256;
    const float* hpp = hp + jh * 256;
    const float* avp = av + jh * 256;
    float a = 0;
#pragma unroll 4
    for (int j = 0; j < 256; j++) a += avp[j] * tanh_(hpp[j] + ep[j]);
    part[tid] = a;
  }
  __syncthreads();
  if (tid < S) {
    float v = part[tid] + part[tid + 128];
    if (src[b * S + tid] == PAD_IDX) v = -1e10f;
    sc[tid] = v;
  }
  __syncthreads();
  if (tid < 64) {  // max reduce over 128
    float v = fmaxf(sc[tid], sc[tid + 64]);
    for (int o = 32; o; o >>= 1) v = fmaxf(v, __shfl_down(v, o));
    if (tid == 0) red[0] = v;
  }
  __syncthreads();
  float mx = red[0];
  if (tid < S) sc[tid] = __expf(sc[tid] - mx);
  __syncthreads();
  if (tid < 64) {  // sum reduce
    float v = sc[tid] + sc[tid + 64];
    for (int o = 32; o; o >>= 1) v += __shfl_down(v, o);
    if (tid == 0) red[0] = v;
  }
  __syncthreads();
  float inv = 1.f / red[0];
#pragma unroll
  for (int rep = 0; rep < 2; rep++) {  // weighted = a @ enc_bt
    int col = tid + rep * 256;
    const float* eb = enc_bt + (long)b * S * H + col;
    float a = 0;
#pragma unroll 4
    for (int s2 = 0; s2 < S; s2++) a += sc[s2] * eb[(long)s2 * H];
    a *= inv;
    weighted[b * H + col] = a;
    xout[((long)t * B + b) * KOUT + H + col] = f2bf(a);
  }
}

// ---------------- decoder LSTM step ----------------------------------------
__global__ __launch_bounds__(256) void lstm_dec_step(
    const float* __restrict__ eih,  // [B,H4] this step (emb part + biases)
    const float* __restrict__ wih,  // dec_wih [H4, 2H]; cols H.. = weighted
    const float* __restrict__ whh,  // dec_whh [H4, H]
    const float* __restrict__ h_in, float* __restrict__ h_out,
    float* __restrict__ c, const float* __restrict__ weighted,
    u16* __restrict__ xout, int t) {
  __shared__ float hs[H], wsd[H];
  int tid = threadIdx.x;
  int b = blockIdx.x >> 1, half = blockIdx.x & 1, j = half * 256 + tid;
  hs[tid] = h_in[b * H + tid];
  hs[tid + 256] = h_in[b * H + 256 + tid];
  wsd[tid] = weighted[b * H + tid];
  wsd[tid + 256] = weighted[b * H + 256 + tid];
  __syncthreads();
  const float4* hv = (const float4*)hs;
  const float4* wv = (const float4*)wsd;
  const float4* wi0 = (const float4*)(wih + (long)j * (2 * H) + H);
  const float4* wi1 = (const float4*)(wih + (long)(H + j) * (2 * H) + H);
  const float4* wi2 = (const float4*)(wih + (long)(2 * H + j) * (2 * H) + H);
  const float4* wi3 = (const float4*)(wih + (long)(3 * H + j) * (2 * H) + H);
  const float4* wh0 = (const float4*)(whh + (long)j * H);
  const float4* wh1 = (const float4*)(whh + (long)(H + j) * H);
  const float4* wh2 = (const float4*)(whh + (long)(2 * H + j) * H);
  const float4* wh3 = (const float4*)(whh + (long)(3 * H + j) * H);
  float a0 = 0, a1 = 0, a2 = 0, a3 = 0;
#pragma unroll 2
  for (int k = 0; k < H / 4; k++) {
    float4 h4 = hv[k], s4 = wv[k];
    a0 += dot4(s4, wi0[k]) + dot4(h4, wh0[k]);
    a1 += dot4(s4, wi1[k]) + dot4(h4, wh1[k]);
    a2 += dot4(s4, wi2[k]) + dot4(h4, wh2[k]);
    a3 += dot4(s4, wi3[k]) + dot4(h4, wh3[k]);
  }
  long xb = (long)b * H4;
  float gi = eih[xb + j] + a0;
  float gf = eih[xb + H + j] + a1;
  float gg = eih[xb + 2 * H + j] + a2;
  float go = eih[xb + 3 * H + j] + a3;
  float cn = sigm(gf) * c[b * H + j] + sigm(gi) * tanh_(gg);
  c[b * H + j] = cn;
  float hn = sigm(go) * tanh_(cn);
  h_out[b * H + j] = hn;
  xout[((long)t * B + b) * KOUT + j] = f2bf(hn);
}

// ---------------------------------------------------------------------------
extern "C" void kernel_launch(void* const* d_in, const int* in_sizes, int n_in,
                              void* d_out, int out_size, void* d_ws,
                              size_t ws_size, hipStream_t stream) {
  const int* src = (const int*)d_in[0];
  const int* trg = (const int*)d_in[2];
  const float* enc_emb = (const float*)d_in[3];
  const float* enc_wih = (const float*)d_in[4];
  const float* enc_whh = (const float*)d_in[5];
  const float* enc_bih = (const float*)d_in[6];
  const float* enc_bhh = (const float*)d_in[7];
  const float* fc_w = (const float*)d_in[8];
  const float* fc_b = (const float*)d_in[9];
  const float* dec_emb = (const float*)d_in[10];
  const float* attn_w = (const float*)d_in[11];
  const float* attn_b = (const float*)d_in[12];
  const float* attn_v = (const float*)d_in[13];
  const float* dec_wih = (const float*)d_in[14];
  const float* dec_whh = (const float*)d_in[15];
  const float* dec_bih = (const float*)d_in[16];
  const float* dec_bhh = (const float*)d_in[17];
  const float* out_w = (const float*)d_in[18];
  const float* out_b = (const float*)d_in[19];
  float* out = (float*)d_out;

  char* wp = (char*)d_ws;
  auto alloc = [&](size_t n) {
    char* p = wp;
    wp += (n + 255) & ~(size_t)255;
    return p;
  };
  u16* outw_bf = (u16*)alloc((size_t)V * KOUT * 2);        // 98.3 MB
  u16* xemb_bf = (u16*)alloc((size_t)S * B * H * 2);       // 4.2 MB
  u16* wihenc_bf = (u16*)alloc((size_t)H4 * H * 2);        // 2.1 MB
  u16* attnw2_bf = (u16*)alloc((size_t)H * H * 2);         // 0.5 MB
  u16* wihE_bf = (u16*)alloc((size_t)H4 * H * 2);          // 2.1 MB
  float* xih = (float*)alloc((size_t)S * B * H4 * 4);      // 33.6 MB
  float* enc_bt = (float*)alloc((size_t)B * S * H * 4);    // 8.4 MB
  u16* enc_bt_bf = (u16*)alloc((size_t)B * S * H * 2);     // 4.2 MB
  float* epart = (float*)alloc((size_t)B * S * H * 4);     // 8.4 MB
  float* eih = (float*)alloc((size_t)MOUT * H4 * 4);       // 16.5 MB
  u16* xout_bf = (u16*)alloc((size_t)MOUT * KOUT * 2);     // 6.2 MB
  float* hb0 = (float*)alloc((size_t)B * H * 4);
  float* hb1 = (float*)alloc((size_t)B * H * 4);
  float* cbuf = (float*)alloc((size_t)B * H * 4);
  float* wbuf = (float*)alloc((size_t)B * H * 4);
  float* benc = (float*)alloc((size_t)H4 * 4);
  float* bdec = (float*)alloc((size_t)H4 * 4);

  dim3 blk(256);
  // init state + out[0] block
  zero_f<<<dim3(64), blk, 0, stream>>>(hb0, (long)B * H);
  zero_f<<<dim3(64), blk, 0, stream>>>(cbuf, (long)B * H);
  zero_f<<<dim3(256), blk, 0, stream>>>(out, (long)B * V);
  // weight casts / packs
  cast_bf<<<dim3(KOUT / 256, V), blk, 0, stream>>>(out_w, outw_bf, KOUT, 0, KOUT);
  cast_bf<<<dim3(H / 256, H4), blk, 0, stream>>>(enc_wih, wihenc_bf, H, 0, H);
  cast_bf<<<dim3(H / 256, H), blk, 0, stream>>>(attn_w, attnw2_bf, 2 * H, H, H);
  cast_bf<<<dim3(H / 256, H4), blk, 0, stream>>>(dec_wih, wihE_bf, 2 * H, 0, H);
  bias_sum<<<dim3(H4 / 256), blk, 0, stream>>>(enc_bih, enc_bhh, benc);
  bias_sum<<<dim3(H4 / 256), blk, 0, stream>>>(dec_bih, dec_bhh, bdec);
  // encoder input-side GEMM for all timesteps at once
  gather_src_emb<<<dim3(H / 256, S * B), blk, 0, stream>>>(src, enc_emb, xemb_bf);
  gemm_bt<<<dim3(H4 / 128, (S * B) / 128), blk, 0, stream>>>(
      xemb_bf, H, wihenc_bf, H, xih, H4, benc, S * B, H);
  // encoder recurrence (ping-pong h)
  for (int t = 0; t < S; t++) {
    const float* hin = (t & 1) ? hb1 : hb0;
    float* hout = (t & 1) ? hb0 : hb1;
    lstm_enc_step<<<dim3(2 * B), blk, 0, stream>>>(
        xih + (size_t)t * B * H4, enc_whh, hin, hout, cbuf, enc_bt, enc_bt_bf, t);
  }
  // hf is in hb0 (S even); hidden -> hb1; c carries over in cbuf
  fc_tanh<<<dim3(2 * B), blk, 0, stream>>>(hb0, fc_w, fc_b, hb1);
  // Epart = enc_bt @ W2^T + attn_b  (step-invariant attention part)
  gemm_bt<<<dim3(H / 128, (B * S) / 128), blk, 0, stream>>>(
      enc_bt_bf, H, attnw2_bf, H, epart, H, attn_b, B * S, H);
  // decoder embeddings -> xout e-slot, then Eih = e @ WihE^T + (bih+bhh)
  gather_trg_emb<<<dim3(H / 256, MOUT), blk, 0, stream>>>(trg, dec_emb, xout_bf);
  gemm_bt<<<dim3(H4 / 128, (MOUT + 127) / 128), blk, 0, stream>>>(
      xout_bf + 2 * H, KOUT, wihE_bf, H, eih, H4, bdec, MOUT, H);
  // decoder recurrence
  for (int t = 0; t < TD; t++) {
    const float* hin = (t & 1) ? hb0 : hb1;
    float* hout = (t & 1) ? hb1 : hb0;
    attn_step<<<dim3(B), blk, 0, stream>>>(hin, attn_w, attn_v, epart, enc_bt,
                                           src, wbuf, xout_bf, t);
    lstm_dec_step<<<dim3(2 * B), blk, 0, stream>>>(
        eih + (size_t)t * B * H4, dec_wih, dec_whh, hin, hout, cbuf, wbuf,
        xout_bf, t);
  }
  // big output GEMM: logits[2016, 32000] = xout @ out_w^T + out_b
  gemm_bt<<<dim3(V / 128, (MOUT + 127) / 128), blk, 0, stream>>>(
      xout_bf, KOUT, outw_bf, KOUT, out + (size_t)B * V, V, out_b, MOUT, KOUT);
}

// Round 2
// 9203.117 us; speedup vs baseline: 2.4038x; 2.4038x over previous
//
#include <hip/hip_runtime.h>

typedef unsigned short u16;
typedef __attribute__((ext_vector_type(8))) short bf16x8;
typedef __attribute__((ext_vector_type(8))) unsigned short u16x8;
typedef __attribute__((ext_vector_type(4))) unsigned short u16x4;
typedef __attribute__((ext_vector_type(4))) float f32x4;

#define DEVI static __device__ __forceinline__

constexpr int B = 32, S = 128, T = 64, H = 512, V = 32000;
constexpr int H4 = 4 * H;          // 2048
constexpr int TD = T - 1;          // 63 decoder steps
constexpr int MOUT = TD * B;       // 2016
constexpr int KOUT = 3 * H;        // 1536
constexpr int PAD_IDX = 1;

DEVI u16 f2bf(float f) {
  union { float f; unsigned u; } v; v.f = f;
  unsigned r = (v.u + 0x7fffu + ((v.u >> 16) & 1u)) >> 16;
  return (u16)r;
}
DEVI float sigm(float x) { return 1.f / (1.f + __expf(-x)); }
DEVI float tanh_(float x) {
  float ax = fabsf(x);
  float e = __expf(-2.f * ax);
  float t = (1.f - e) / (1.f + e);
  return x < 0.f ? -t : t;
}
DEVI int swz(int row, int k8) { return row * 32 + ((k8 ^ (row & 3)) << 3); }

// ---------------- bf16 MFMA GEMM:  C[M,N] = A[M,K] * Bt[N,K]^T + bias ------
__global__ __launch_bounds__(256) void gemm_bt(
    const u16* __restrict__ A, int lda,
    const u16* __restrict__ Bt, int ldb,
    float* __restrict__ C, int ldc,
    const float* __restrict__ bias, int M, int K) {
  __shared__ u16 As[128 * 32], Bs[128 * 32];
  const int tid = threadIdx.x;
  const int m0 = blockIdx.y * 128, n0 = blockIdx.x * 128;
  const int lane = tid & 63, w = tid >> 6, wm = w >> 1, wn = w & 1;
  const int lr = lane & 15, lk = lane >> 4;
  f32x4 acc[4][4] = {};
  const int r = tid >> 1, cc = (tid & 1) * 16, k8b = (tid & 1) * 2;

  for (int k0 = 0; k0 < K; k0 += 32) {
    {
      long gr = m0 + r;
      u16x8 v0 = {}, v1 = {};
      if (gr < M) {
        const u16* s = A + gr * (long)lda + k0 + cc;
        v0 = *(const u16x8*)s;
        v1 = *(const u16x8*)(s + 8);
      }
      *(u16x8*)&As[swz(r, k8b)] = v0;
      *(u16x8*)&As[swz(r, k8b + 1)] = v1;
    }
    {
      const u16* s = Bt + (long)(n0 + r) * ldb + k0 + cc;
      u16x8 v0 = *(const u16x8*)s;
      u16x8 v1 = *(const u16x8*)(s + 8);
      *(u16x8*)&Bs[swz(r, k8b)] = v0;
      *(u16x8*)&Bs[swz(r, k8b + 1)] = v1;
    }
    __syncthreads();
    bf16x8 af[4], bfr[4];
#pragma unroll
    for (int mi = 0; mi < 4; mi++)
      af[mi] = *(const bf16x8*)&As[swz(wm * 64 + mi * 16 + lr, lk)];
#pragma unroll
    for (int ni = 0; ni < 4; ni++)
      bfr[ni] = *(const bf16x8*)&Bs[swz(wn * 64 + ni * 16 + lr, lk)];
#pragma unroll
    for (int mi = 0; mi < 4; mi++)
#pragma unroll
      for (int ni = 0; ni < 4; ni++)
        acc[mi][ni] = __builtin_amdgcn_mfma_f32_16x16x32_bf16(
            af[mi], bfr[ni], acc[mi][ni], 0, 0, 0);
    __syncthreads();
  }
#pragma unroll
  for (int ni = 0; ni < 4; ni++) {
    int col = n0 + wn * 64 + ni * 16 + lr;
    float bs = bias ? bias[col] : 0.f;
#pragma unroll
    for (int mi = 0; mi < 4; mi++) {
#pragma unroll
      for (int rr = 0; rr < 4; rr++) {
        long row = m0 + wm * 64 + mi * 16 + lk * 4 + rr;
        if (row < M) C[row * (long)ldc + col] = acc[mi][ni][rr] + bs;
      }
    }
  }
}

// ---------------- helpers ---------------------------------------------------
__global__ void zero_f(float* p, long n) {
  long i = (long)blockIdx.x * 256 + threadIdx.x;
  long st = (long)gridDim.x * 256;
  for (; i < n; i += st) p[i] = 0.f;
}

__global__ void cast_bf(const float* __restrict__ src, u16* __restrict__ dst,
                        int ld, int off, int Csz) {
  long row = blockIdx.y;
  int col = blockIdx.x * 256 + threadIdx.x;
  dst[row * Csz + col] = f2bf(src[row * ld + off + col]);
}

// contiguous float->bf16, 4 elems/thread
__global__ void cast_bf4(const float* __restrict__ src, u16* __restrict__ dst,
                         long n4) {
  long i = (long)blockIdx.x * 256 + threadIdx.x;
  if (i >= n4) return;
  float4 v = ((const float4*)src)[i];
  u16x4 o;
  o[0] = f2bf(v.x); o[1] = f2bf(v.y); o[2] = f2bf(v.z); o[3] = f2bf(v.w);
  *(u16x4*)&dst[i * 4] = o;
}

__global__ void bias_sum(const float* __restrict__ a,
                         const float* __restrict__ b, float* __restrict__ o) {
  int i = blockIdx.x * 256 + threadIdx.x;
  o[i] = a[i] + b[i];
}

// dst[c*R + r] = src[r*ld + off + c]; grid (C/32, R/32), block 256
__global__ __launch_bounds__(256) void transpose_f(
    const float* __restrict__ src, int ld, int off, float* __restrict__ dst,
    int R, int C) {
  __shared__ float tile[32][33];
  int r0 = blockIdx.y * 32, c0 = blockIdx.x * 32;
  int tx = threadIdx.x & 31, ty = threadIdx.x >> 5;  // 32 x 8
#pragma unroll
  for (int i = 0; i < 32; i += 8)
    tile[ty + i][tx] = src[(long)(r0 + ty + i) * ld + off + c0 + tx];
  __syncthreads();
#pragma unroll
  for (int i = 0; i < 32; i += 8)
    dst[(long)(c0 + ty + i) * R + r0 + tx] = tile[tx][ty + i];
}

__global__ void gather_src_emb(const int* __restrict__ src,
                               const float* __restrict__ emb,
                               u16* __restrict__ dst) {
  int row = blockIdx.y;           // row = t*B + b
  int t = row >> 5, b = row & 31;
  int c = blockIdx.x * 256 + threadIdx.x;
  int tok = src[b * S + t];
  dst[(long)row * H + c] = f2bf(emb[(long)tok * H + c]);
}

__global__ void gather_trg_emb(const int* __restrict__ trg,
                               const float* __restrict__ emb,
                               u16* __restrict__ xout) {
  int row = blockIdx.y;           // row = t*B + b, t < 63
  int t = row >> 5, b = row & 31;
  int c = blockIdx.x * 256 + threadIdx.x;
  int tok = trg[b * T + t];
  xout[(long)row * KOUT + 2 * H + c] = f2bf(emb[(long)tok * H + c]);
}

// ---- generic H->H matvec: out[b,j] = act(x[b,:]·wT[:,j] + bias) -----------
// grid 256 blocks (8 bq x 32 jc), 64 threads (4 b x 16 j)
__global__ __launch_bounds__(64) void mv512(
    const float* __restrict__ x, const float* __restrict__ wT,
    const float* __restrict__ bias, float* __restrict__ out, int act) {
  __shared__ float hs[4][H];
  const int tid = threadIdx.x;
  const int bq = blockIdx.x >> 5, jc = blockIdx.x & 31;
  const int b_in = tid >> 4, j_in = tid & 15;
  const int j = jc * 16 + j_in, b = bq * 4 + b_in;
  for (int i = tid; i < 4 * H; i += 64)
    hs[i >> 9][i & (H - 1)] = x[(bq * 4 + (i >> 9)) * H + (i & (H - 1))];
  __syncthreads();
  const float* wp = wT + j;
  float a = 0.f;
#pragma unroll 8
  for (int k = 0; k < H; k++) a += hs[b_in][k] * wp[(size_t)k * H];
  if (bias) a += bias[j];
  out[b * H + j] = act ? tanh_(a) : a;
}

// ---------------- fused encoder LSTM step ----------------------------------
// grid 256 (8 bq x 32 jc), block 256 (4 b x 4 gate x 16 j); whhT [H][H4]
__global__ __launch_bounds__(256) void enc_step(
    const float* __restrict__ xih, const float* __restrict__ whhT,
    const float* __restrict__ h_in, float* __restrict__ h_out,
    float* __restrict__ c, float* __restrict__ enc_bt,
    u16* __restrict__ enc_bt_bf, int t) {
  __shared__ float hs[4][H];
  __shared__ float gs[256];
  const int tid = threadIdx.x;
  const int bq = blockIdx.x >> 5, jc = blockIdx.x & 31;
  const int b_in = tid >> 6, rem = tid & 63, g = rem >> 4, j_in = rem & 15;
  const int j = jc * 16 + j_in;
  for (int i = tid; i < 4 * H; i += 256)
    hs[i >> 9][i & (H - 1)] = h_in[(bq * 4 + (i >> 9)) * H + (i & (H - 1))];
  __syncthreads();
  const float* wp = whhT + g * H + j;
  const float* hb = hs[b_in];
  float a = 0.f;
#pragma unroll 8
  for (int k = 0; k < H; k++) a += hb[k] * wp[(size_t)k * H4];
  gs[tid] = a;
  __syncthreads();
  if (tid < 64) {
    const int bi = tid >> 4, jl = jc * 16 + (tid & 15), b = bq * 4 + bi;
    const float* gp = gs + bi * 64 + (tid & 15);
    const long xb = (long)b * H4;
    float gi = xih[xb + jl] + gp[0];
    float gf = xih[xb + H + jl] + gp[16];
    float gg = xih[xb + 2 * H + jl] + gp[32];
    float go = xih[xb + 3 * H + jl] + gp[48];
    float cn = sigm(gf) * c[b * H + jl] + sigm(gi) * tanh_(gg);
    c[b * H + jl] = cn;
    float hn = sigm(go) * tanh_(cn);
    h_out[b * H + jl] = hn;
    long ei = ((long)b * S + t) * H + jl;
    enc_bt[ei] = hn;
    enc_bt_bf[ei] = f2bf(hn);
  }
}

// ---------------- fused decoder LSTM step ----------------------------------
// WdecT [2H][H4]: rows 0..H-1 = wih weighted-part^T, rows H.. = whh^T
__global__ __launch_bounds__(256) void dec_step(
    const float* __restrict__ eih, const float* __restrict__ WdecT,
    const float* __restrict__ h_in, float* __restrict__ h_out,
    float* __restrict__ c, const float* __restrict__ weighted,
    u16* __restrict__ xout, int t) {
  __shared__ float xs[4][2 * H];
  __shared__ float gs[256];
  const int tid = threadIdx.x;
  const int bq = blockIdx.x >> 5, jc = blockIdx.x & 31;
  const int b_in = tid >> 6, rem = tid & 63, g = rem >> 4, j_in = rem & 15;
  const int j = jc * 16 + j_in;
  for (int i = tid; i < 4 * 2 * H; i += 256) {
    int bi = i >> 10, kk = i & (2 * H - 1);
    int b = bq * 4 + bi;
    xs[bi][kk] = kk < H ? weighted[b * H + kk] : h_in[b * H + kk - H];
  }
  __syncthreads();
  const float* wp = WdecT + g * H + j;
  const float* xb = xs[b_in];
  float a = 0.f;
#pragma unroll 8
  for (int k = 0; k < 2 * H; k++) a += xb[k] * wp[(size_t)k * H4];
  gs[tid] = a;
  __syncthreads();
  if (tid < 64) {
    const int bi = tid >> 4, jl = jc * 16 + (tid & 15), b = bq * 4 + bi;
    const float* gp = gs + bi * 64 + (tid & 15);
    const long xb2 = (long)b * H4;
    float gi = eih[xb2 + jl] + gp[0];
    float gf = eih[xb2 + H + jl] + gp[16];
    float gg = eih[xb2 + 2 * H + jl] + gp[32];
    float go = eih[xb2 + 3 * H + jl] + gp[48];
    float cn = sigm(gf) * c[b * H + jl] + sigm(gi) * tanh_(gg);
    c[b * H + jl] = cn;
    float hn = sigm(go) * tanh_(cn);
    h_out[b * H + jl] = hn;
    xout[((long)t * B + b) * KOUT + jl] = f2bf(hn);
  }
}

// ---------------- attention: scores + softmax + weighted -------------------
// grid B blocks, 512 threads (8 waves)
__global__ __launch_bounds__(512) void attn_sw(
    const float* __restrict__ hp_buf, const float* __restrict__ attn_v,
    const float* __restrict__ epart, const float* __restrict__ enc_bt,
    const int* __restrict__ src, float* __restrict__ weighted,
    u16* __restrict__ xout, int t) {
  __shared__ float hp[H], av[H], sc[S], red[1];
  const int tid = threadIdx.x, b = blockIdx.x;
  hp[tid] = hp_buf[b * H + tid];
  av[tid] = attn_v[tid];
  __syncthreads();
  {
    const int w = tid >> 6, lane = tid & 63;
    for (int s16 = 0; s16 < 16; s16++) {
      int s = w * 16 + s16;
      const float* ep = epart + ((long)b * S + s) * H;
      float a = 0.f;
#pragma unroll
      for (int jcc = 0; jcc < 8; jcc++) {
        int j = jcc * 64 + lane;
        a += av[j] * tanh_(hp[j] + ep[j]);
      }
      for (int o = 32; o; o >>= 1) a += __shfl_xor(a, o);
      if (lane == 0) sc[s] = a;
    }
  }
  __syncthreads();
  if (tid < S && src[b * S + tid] == PAD_IDX) sc[tid] = -1e10f;
  __syncthreads();
  if (tid < 64) {
    float v = fmaxf(sc[tid], sc[tid + 64]);
    for (int o = 32; o; o >>= 1) v = fmaxf(v, __shfl_xor(v, o));
    if (tid == 0) red[0] = v;
  }
  __syncthreads();
  float mx = red[0];
  if (tid < S) sc[tid] = __expf(sc[tid] - mx);
  __syncthreads();
  if (tid < 64) {
    float v = sc[tid] + sc[tid + 64];
    for (int o = 32; o; o >>= 1) v += __shfl_xor(v, o);
    if (tid == 0) red[0] = v;
  }
  __syncthreads();
  const float inv = 1.f / red[0];
  {
    const float* eb = enc_bt + (long)b * S * H + tid;
    float a = 0.f;
#pragma unroll 4
    for (int s2 = 0; s2 < S; s2++) a += sc[s2] * eb[(size_t)s2 * H];
    a *= inv;
    weighted[b * H + tid] = a;
    xout[((long)t * B + b) * KOUT + H + tid] = f2bf(a);
  }
}

// ---------------------------------------------------------------------------
extern "C" void kernel_launch(void* const* d_in, const int* in_sizes, int n_in,
                              void* d_out, int out_size, void* d_ws,
                              size_t ws_size, hipStream_t stream) {
  const int* src = (const int*)d_in[0];
  const int* trg = (const int*)d_in[2];
  const float* enc_emb = (const float*)d_in[3];
  const float* enc_wih = (const float*)d_in[4];
  const float* enc_whh = (const float*)d_in[5];
  const float* enc_bih = (const float*)d_in[6];
  const float* enc_bhh = (const float*)d_in[7];
  const float* fc_w = (const float*)d_in[8];
  const float* fc_b = (const float*)d_in[9];
  const float* dec_emb = (const float*)d_in[10];
  const float* attn_w = (const float*)d_in[11];
  const float* attn_b = (const float*)d_in[12];
  const float* attn_v = (const float*)d_in[13];
  const float* dec_wih = (const float*)d_in[14];
  const float* dec_whh = (const float*)d_in[15];
  const float* dec_bih = (const float*)d_in[16];
  const float* dec_bhh = (const float*)d_in[17];
  const float* out_w = (const float*)d_in[18];
  const float* out_b = (const float*)d_in[19];
  float* out = (float*)d_out;

  char* wp = (char*)d_ws;
  auto alloc = [&](size_t n) {
    char* p = wp;
    wp += (n + 255) & ~(size_t)255;
    return p;
  };
  u16* outw_bf = (u16*)alloc((size_t)V * KOUT * 2);        // 98.3 MB
  u16* xemb_bf = (u16*)alloc((size_t)S * B * H * 2);       // 4.2 MB
  u16* wihenc_bf = (u16*)alloc((size_t)H4 * H * 2);        // 2.1 MB
  u16* attnw2_bf = (u16*)alloc((size_t)H * H * 2);         // 0.5 MB
  u16* wihE_bf = (u16*)alloc((size_t)H4 * H * 2);          // 2.1 MB
  float* xih = (float*)alloc((size_t)S * B * H4 * 4);      // 33.6 MB
  float* enc_bt = (float*)alloc((size_t)B * S * H * 4);    // 8.4 MB
  u16* enc_bt_bf = (u16*)alloc((size_t)B * S * H * 2);     // 4.2 MB
  float* epart = (float*)alloc((size_t)B * S * H * 4);     // 8.4 MB
  float* eih = (float*)alloc((size_t)MOUT * H4 * 4);       // 16.5 MB
  u16* xout_bf = (u16*)alloc((size_t)MOUT * KOUT * 2);     // 6.2 MB
  float* whhT = (float*)alloc((size_t)H * H4 * 4);         // 4.2 MB
  float* WdecT = (float*)alloc((size_t)2 * H * H4 * 4);    // 8.4 MB
  float* a1T = (float*)alloc((size_t)H * H * 4);           // 1 MB
  float* fcT = (float*)alloc((size_t)H * H * 4);           // 1 MB
  float* hp_buf = (float*)alloc((size_t)B * H * 4);
  float* hb0 = (float*)alloc((size_t)B * H * 4);
  float* hb1 = (float*)alloc((size_t)B * H * 4);
  float* cbuf = (float*)alloc((size_t)B * H * 4);
  float* wbuf = (float*)alloc((size_t)B * H * 4);
  float* benc = (float*)alloc((size_t)H4 * 4);
  float* bdec = (float*)alloc((size_t)H4 * 4);

  dim3 blk(256);
  // init state + out[0] block
  zero_f<<<dim3(64), blk, 0, stream>>>(hb0, (long)B * H);
  zero_f<<<dim3(64), blk, 0, stream>>>(cbuf, (long)B * H);
  zero_f<<<dim3(256), blk, 0, stream>>>(out, (long)B * V);
  // weight casts / packs / transposes
  cast_bf4<<<dim3(((long)V * KOUT / 4 + 255) / 256), blk, 0, stream>>>(
      out_w, outw_bf, (long)V * KOUT / 4);
  cast_bf<<<dim3(H / 256, H4), blk, 0, stream>>>(enc_wih, wihenc_bf, H, 0, H);
  cast_bf<<<dim3(H / 256, H), blk, 0, stream>>>(attn_w, attnw2_bf, 2 * H, H, H);
  cast_bf<<<dim3(H / 256, H4), blk, 0, stream>>>(dec_wih, wihE_bf, 2 * H, 0, H);
  bias_sum<<<dim3(H4 / 256), blk, 0, stream>>>(enc_bih, enc_bhh, benc);
  bias_sum<<<dim3(H4 / 256), blk, 0, stream>>>(dec_bih, dec_bhh, bdec);
  transpose_f<<<dim3(H / 32, H4 / 32), blk, 0, stream>>>(enc_whh, H, 0, whhT,
                                                         H4, H);
  transpose_f<<<dim3(H / 32, H4 / 32), blk, 0, stream>>>(dec_wih, 2 * H, H,
                                                         WdecT, H4, H);
  transpose_f<<<dim3(H / 32, H4 / 32), blk, 0, stream>>>(
      dec_whh, H, 0, WdecT + (size_t)H * H4, H4, H);
  transpose_f<<<dim3(H / 32, H / 32), blk, 0, stream>>>(attn_w, 2 * H, 0, a1T,
                                                        H, H);
  transpose_f<<<dim3(H / 32, H / 32), blk, 0, stream>>>(fc_w, H, 0, fcT, H, H);
  // encoder input-side GEMM for all timesteps at once
  gather_src_emb<<<dim3(H / 256, S * B), blk, 0, stream>>>(src, enc_emb,
                                                           xemb_bf);
  gemm_bt<<<dim3(H4 / 128, (S * B) / 128), blk, 0, stream>>>(
      xemb_bf, H, wihenc_bf, H, xih, H4, benc, S * B, H);
  // encoder recurrence (ping-pong h)
  for (int t = 0; t < S; t++) {
    const float* hin = (t & 1) ? hb1 : hb0;
    float* hout = (t & 1) ? hb0 : hb1;
    enc_step<<<dim3(256), blk, 0, stream>>>(xih + (size_t)t * B * H4, whhT, hin,
                                            hout, cbuf, enc_bt, enc_bt_bf, t);
  }
  // hf is in hb0 (S even); hidden -> hb1
  mv512<<<dim3(256), dim3(64), 0, stream>>>(hb0, fcT, fc_b, hb1, 1);
  // Epart = enc_bt @ W2^T + attn_b
  gemm_bt<<<dim3(H / 128, (B * S) / 128), blk, 0, stream>>>(
      enc_bt_bf, H, attnw2_bf, H, epart, H, attn_b, B * S, H);
  // decoder embeddings -> xout e-slot, then Eih = e @ WihE^T + (bih+bhh)
  gather_trg_emb<<<dim3(H / 256, MOUT), blk, 0, stream>>>(trg, dec_emb,
                                                          xout_bf);
  gemm_bt<<<dim3(H4 / 128, (MOUT + 127) / 128), blk, 0, stream>>>(
      xout_bf + 2 * H, KOUT, wihE_bf, H, eih, H4, bdec, MOUT, H);
  // decoder recurrence
  for (int t = 0; t < TD; t++) {
    const float* hin = (t & 1) ? hb0 : hb1;
    float* hout = (t & 1) ? hb1 : hb0;
    mv512<<<dim3(256), dim3(64), 0, stream>>>(hin, a1T, nullptr, hp_buf, 0);
    attn_sw<<<dim3(B), dim3(512), 0, stream>>>(hp_buf, attn_v, epart, enc_bt,
                                               src, wbuf, xout_bf, t);
    dec_step<<<dim3(256), blk, 0, stream>>>(eih + (size_t)t * B * H4, WdecT,
                                            hin, hout, cbuf, wbuf, xout_bf, t);
  }
  // big output GEMM: logits[2016, 32000] = xout @ out_w^T + out_b
  gemm_bt<<<dim3(V / 128, (MOUT + 127) / 128), blk, 0, stream>>>(
      xout_bf, KOUT, outw_bf, KOUT, out + (size_t)B * V, V, out_b, MOUT, KOUT);
}

// Round 4
// 6183.771 us; speedup vs baseline: 3.5776x; 1.4883x over previous
//
#include <hip/hip_runtime.h>

typedef unsigned short u16;
typedef __attribute__((ext_vector_type(8))) short bf16x8;
typedef __attribute__((ext_vector_type(8))) unsigned short u16x8;
typedef __attribute__((ext_vector_type(4))) unsigned short u16x4;
typedef __attribute__((ext_vector_type(4))) float f32x4;

#define DEVI static __device__ __forceinline__

constexpr int B = 32, S = 128, T = 64, H = 512, V = 32000;
constexpr int H4 = 4 * H;          // 2048
constexpr int TD = T - 1;          // 63 decoder steps
constexpr int MOUT = TD * B;       // 2016
constexpr int KOUT = 3 * H;        // 1536
constexpr int PAD_IDX = 1;

DEVI u16 f2bf(float f) {
  union { float f; unsigned u; } v; v.f = f;
  unsigned r = (v.u + 0x7fffu + ((v.u >> 16) & 1u)) >> 16;
  return (u16)r;
}
DEVI float bf2f(u16 h) {
  union { unsigned u; float f; } v; v.u = ((unsigned)h) << 16;
  return v.f;
}
DEVI float sigm(float x) { return 1.f / (1.f + __expf(-x)); }
DEVI float tanh_(float x) {
  float ax = fabsf(x);
  float e = __expf(-2.f * ax);
  float t = (1.f - e) / (1.f + e);
  return x < 0.f ? -t : t;
}
DEVI int swz(int row, int k8) { return row * 32 + ((k8 ^ (row & 3)) << 3); }

// ---- grid barrier: counter at bar[0], generation at bar[32] (sep lines) ----
// Call #expect must match monotonically increasing generation.
DEVI void gbar(unsigned* bar, int* dead, int expect) {
  __syncthreads();
  if (threadIdx.x == 0 && !*dead) {
    unsigned a = __hip_atomic_fetch_add(bar, 1u, __ATOMIC_ACQ_REL,
                                        __HIP_MEMORY_SCOPE_AGENT);
    if (a == gridDim.x - 1) {
      __hip_atomic_store(bar, 0u, __ATOMIC_RELAXED, __HIP_MEMORY_SCOPE_AGENT);
      __hip_atomic_fetch_add(bar + 32, 1u, __ATOMIC_ACQ_REL,
                             __HIP_MEMORY_SCOPE_AGENT);
    } else {
      long long t0 = (long long)__builtin_amdgcn_s_memrealtime();
      while ((int)__hip_atomic_load(bar + 32, __ATOMIC_ACQUIRE,
                                    __HIP_MEMORY_SCOPE_AGENT) < expect) {
        __builtin_amdgcn_s_sleep(8);
        if ((long long)__builtin_amdgcn_s_memrealtime() - t0 > 20000000ll) {
          *dead = 1;
          break;
        }
      }
    }
  }
  __syncthreads();
}

// ---------------- bf16 MFMA GEMM:  C[M,N] = A[M,K] * Bt[N,K]^T + bias ------
__global__ __launch_bounds__(256) void gemm_bt(
    const u16* __restrict__ A, int lda,
    const u16* __restrict__ Bt, int ldb,
    float* __restrict__ C, int ldc,
    const float* __restrict__ bias, int M, int K, int bf16out) {
  __shared__ u16 As[128 * 32], Bs[128 * 32];
  const int tid = threadIdx.x;
  const int m0 = blockIdx.y * 128, n0 = blockIdx.x * 128;
  const int lane = tid & 63, w = tid >> 6, wm = w >> 1, wn = w & 1;
  const int lr = lane & 15, lk = lane >> 4;
  f32x4 acc[4][4] = {};
  const int r = tid >> 1, cc = (tid & 1) * 16, k8b = (tid & 1) * 2;

  for (int k0 = 0; k0 < K; k0 += 32) {
    {
      long gr = m0 + r;
      u16x8 v0 = {}, v1 = {};
      if (gr < M) {
        const u16* s = A + gr * (long)lda + k0 + cc;
        v0 = *(const u16x8*)s;
        v1 = *(const u16x8*)(s + 8);
      }
      *(u16x8*)&As[swz(r, k8b)] = v0;
      *(u16x8*)&As[swz(r, k8b + 1)] = v1;
    }
    {
      const u16* s = Bt + (long)(n0 + r) * ldb + k0 + cc;
      u16x8 v0 = *(const u16x8*)s;
      u16x8 v1 = *(const u16x8*)(s + 8);
      *(u16x8*)&Bs[swz(r, k8b)] = v0;
      *(u16x8*)&Bs[swz(r, k8b + 1)] = v1;
    }
    __syncthreads();
    bf16x8 af[4], bfr[4];
#pragma unroll
    for (int mi = 0; mi < 4; mi++)
      af[mi] = *(const bf16x8*)&As[swz(wm * 64 + mi * 16 + lr, lk)];
#pragma unroll
    for (int ni = 0; ni < 4; ni++)
      bfr[ni] = *(const bf16x8*)&Bs[swz(wn * 64 + ni * 16 + lr, lk)];
#pragma unroll
    for (int mi = 0; mi < 4; mi++)
#pragma unroll
      for (int ni = 0; ni < 4; ni++)
        acc[mi][ni] = __builtin_amdgcn_mfma_f32_16x16x32_bf16(
            af[mi], bfr[ni], acc[mi][ni], 0, 0, 0);
    __syncthreads();
  }
#pragma unroll
  for (int ni = 0; ni < 4; ni++) {
    int col = n0 + wn * 64 + ni * 16 + lr;
    float bs = bias ? bias[col] : 0.f;
#pragma unroll
    for (int mi = 0; mi < 4; mi++) {
#pragma unroll
      for (int rr = 0; rr < 4; rr++) {
        long row = m0 + wm * 64 + mi * 16 + lk * 4 + rr;
        if (row < M) {
          float v = acc[mi][ni][rr] + bs;
          if (bf16out)
            ((u16*)C)[row * (long)ldc + col] = f2bf(v);
          else
            C[row * (long)ldc + col] = v;
        }
      }
    }
  }
}

// ---------------- helpers ---------------------------------------------------
__global__ void zero_f(float* p, long n) {
  long i = (long)blockIdx.x * 256 + threadIdx.x;
  long st = (long)gridDim.x * 256;
  for (; i < n; i += st) p[i] = 0.f;
}

__global__ void zero_u(unsigned* p, int n) {
  int i = threadIdx.x;
  if (i < n) p[i] = 0u;
}

__global__ void cast_bf(const float* __restrict__ src, u16* __restrict__ dst,
                        int ld, int off, int Csz) {
  long row = blockIdx.y;
  int col = blockIdx.x * 256 + threadIdx.x;
  dst[row * Csz + col] = f2bf(src[row * ld + off + col]);
}

__global__ void cast_bf4(const float* __restrict__ src, u16* __restrict__ dst,
                         long n4) {
  long i = (long)blockIdx.x * 256 + threadIdx.x;
  if (i >= n4) return;
  float4 v = ((const float4*)src)[i];
  u16x4 o;
  o[0] = f2bf(v.x); o[1] = f2bf(v.y); o[2] = f2bf(v.z); o[3] = f2bf(v.w);
  *(u16x4*)&dst[i * 4] = o;
}

// permuted-row cast: dst row n' = src row (g*H + jH), n' = jH*4 + g
__global__ void cast_perm(const float* __restrict__ src, int ld, int off,
                          u16* __restrict__ dst) {
  int np = blockIdx.y;
  int c = blockIdx.x * 256 + threadIdx.x;
  int g = np & 3, jH = np >> 2;
  dst[(size_t)np * H + c] = f2bf(src[(size_t)(g * H + jH) * ld + off + c]);
}

__global__ void bias_perm(const float* __restrict__ a,
                          const float* __restrict__ b, float* __restrict__ o) {
  int np = blockIdx.x * 256 + threadIdx.x;
  int g = np & 3, jH = np >> 2;
  int r = g * H + jH;
  o[np] = a[r] + b[r];
}

// dst[c*R + r] = bf16(src[r*ld + off + c]); grid (C/32, R/32)
__global__ __launch_bounds__(256) void cast_transpose_bf(
    const float* __restrict__ src, int ld, int off, u16* __restrict__ dst,
    int R) {
  __shared__ float tile[32][33];
  int r0 = blockIdx.y * 32, c0 = blockIdx.x * 32;
  int tx = threadIdx.x & 31, ty = threadIdx.x >> 5;
#pragma unroll
  for (int i = 0; i < 32; i += 8)
    tile[ty + i][tx] = src[(long)(r0 + ty + i) * ld + off + c0 + tx];
  __syncthreads();
#pragma unroll
  for (int i = 0; i < 32; i += 8)
    dst[(long)(c0 + ty + i) * R + r0 + tx] = f2bf(tile[tx][ty + i]);
}

__global__ void gather_src_emb(const int* __restrict__ src,
                               const float* __restrict__ emb,
                               u16* __restrict__ dst) {
  int row = blockIdx.y;           // row = t*B + b
  int t = row >> 5, b = row & 31;
  int c = blockIdx.x * 256 + threadIdx.x;
  int tok = src[b * S + t];
  dst[(long)row * H + c] = f2bf(emb[(long)tok * H + c]);
}

__global__ void gather_trg_emb(const int* __restrict__ trg,
                               const float* __restrict__ emb,
                               u16* __restrict__ xout) {
  int row = blockIdx.y;           // row = t*B + b, t < 63
  int t = row >> 5, b = row & 31;
  int c = blockIdx.x * 256 + threadIdx.x;
  int tok = trg[b * T + t];
  xout[(long)row * KOUT + 2 * H + c] = f2bf(emb[(long)tok * H + c]);
}

// ---------------- persistent encoder ----------------------------------------
// 128 blocks x 128 threads. Block bk owns jH in [bk*4, bk*4+4) for all gates.
__global__ __launch_bounds__(128) void enc_persist(
    unsigned* bar, const float* __restrict__ whh,
    const float* __restrict__ xih_p, u16* h_pp, u16* enc_bt_bf, float* cbuf) {
  const int tid = threadIdx.x, bk = blockIdx.x;
  const int wave = tid >> 6, lane = tid & 63;
  __shared__ float gs[32][16];
  __shared__ float c_s[128];
  __shared__ int dead;
  if (tid == 0) dead = 0;
  int bc = 0;
  // B-frag preload: lane n=lane&15 -> (g=n&3,q=n>>2); k = kt*32+(lane>>4)*8+e
  bf16x8 wf[16];
  {
    int n = lane & 15, g = n & 3, q = n >> 2;
    const float* wrow = whh + ((size_t)g * H + bk * 4 + q) * H + (lane >> 4) * 8;
#pragma unroll
    for (int kt = 0; kt < 16; kt++) {
      bf16x8 f;
#pragma unroll
      for (int e = 0; e < 8; e++) f[e] = (short)f2bf(wrow[kt * 32 + e]);
      wf[kt] = f;
    }
  }
  c_s[tid] = 0.f;
  {
    int b = tid >> 2, q = tid & 3;
    h_pp[b * H + bk * 4 + q] = 0;  // zero h buffer 0 (own columns)
  }
  gbar(bar, &dead, ++bc);
  for (int t = 0; t < S; t++) {
    const u16* hr = h_pp + (t & 1) * (B * H);
    u16* hw = h_pp + ((t + 1) & 1) * (B * H);
    {
      const u16* hb =
          hr + (size_t)(wave * 16 + (lane & 15)) * H + (lane >> 4) * 8;
      f32x4 acc = {};
#pragma unroll
      for (int kt = 0; kt < 16; kt++) {
        bf16x8 a = *(const bf16x8*)(hb + kt * 32);
        acc = __builtin_amdgcn_mfma_f32_16x16x32_bf16(a, wf[kt], acc, 0, 0, 0);
      }
      int n = lane & 15, r0 = (lane >> 4) * 4;
#pragma unroll
      for (int rr = 0; rr < 4; rr++) gs[wave * 16 + r0 + rr][n] = acc[rr];
    }
    __syncthreads();
    {
      int b = tid >> 2, q = tid & 3;
      float4 xv = *(const float4*)(xih_p + ((size_t)t * B + b) * H4 +
                                   (bk * 4 + q) * 4);
      float gi = xv.x + gs[b][q * 4 + 0];
      float gf = xv.y + gs[b][q * 4 + 1];
      float gg = xv.z + gs[b][q * 4 + 2];
      float go = xv.w + gs[b][q * 4 + 3];
      float cn = sigm(gf) * c_s[tid] + sigm(gi) * tanh_(gg);
      c_s[tid] = cn;
      float hn = sigm(go) * tanh_(cn);
      u16 h16 = f2bf(hn);
      hw[b * H + bk * 4 + q] = h16;
      enc_bt_bf[((size_t)b * S + t) * H + bk * 4 + q] = h16;
    }
    gbar(bar, &dead, ++bc);
  }
  {
    int b = tid >> 2, q = tid & 3;
    cbuf[b * H + bk * 4 + q] = c_s[tid];
  }
}

// ---------------- persistent decoder ----------------------------------------
// 128 blocks x 256 threads, 2 barriers per step.
__global__ __launch_bounds__(256) void dec_persist(
    unsigned* bar, const float* __restrict__ fc_w,
    const float* __restrict__ fc_b, const float* __restrict__ dec_wih,
    const float* __restrict__ dec_whh, const u16* __restrict__ a1T_bf,
    const float* __restrict__ attn_v, const int* __restrict__ src,
    const u16* __restrict__ hf_bf, const float* __restrict__ cbuf,
    const u16* __restrict__ epart_bf, const u16* __restrict__ enc_bt_bf,
    const float* __restrict__ eih_p, u16* hdec, u16* wbuf_bf, u16* xout_bf) {
  const int tid = threadIdx.x, bk = blockIdx.x;
  const int wave = tid >> 6, lane = tid & 63;
  __shared__ u16 Ws[16 * 1024];     // LSTM weights, XOR-swizzled
  __shared__ float gs[32][16];
  __shared__ float c_s[128];
  __shared__ float hs[H], hps[H], avs[H], wsum[4][H], sc[S], red[2];
  __shared__ int smask[S];
  __shared__ int dead;
  if (tid == 0) dead = 0;
  int bc = 0;
  // ---- prologue ----
  for (int idx = tid; idx < 16 * 1024; idx += 256) {
    int n = idx >> 10, k = idx & 1023;
    int g = n & 3, q = n >> 2;
    int grow = g * H + bk * 4 + q;
    float v = (k < 512) ? dec_wih[(size_t)grow * (2 * H) + 512 + k]
                        : dec_whh[(size_t)grow * H + (k - 512)];
    Ws[n * 1024 + (((k >> 3) ^ (n & 7)) << 3) + (k & 7)] = f2bf(v);
  }
  if (tid < 128) c_s[tid] = cbuf[(tid >> 2) * H + bk * 4 + (tid & 3)];
  if (bk < 32) {
    avs[tid] = attn_v[tid];
    avs[tid + 256] = attn_v[tid + 256];
    if (tid < S) smask[tid] = src[bk * S + tid];
  }
  // fc: hidden = tanh(hf @ fc_w^T + fc_b) -> hdec buffer 0 (blocks 0..31)
  if (bk < 32 && wave < 2) {
    int n = lane & 15;
    const u16* hb = hf_bf + (size_t)(wave * 16 + n) * H + (lane >> 4) * 8;
    const float* frow = fc_w + (size_t)(bk * 16 + n) * H + (lane >> 4) * 8;
    f32x4 acc = {};
#pragma unroll
    for (int kt = 0; kt < 16; kt++) {
      bf16x8 a = *(const bf16x8*)(hb + kt * 32);
      bf16x8 bf;
#pragma unroll
      for (int e = 0; e < 8; e++) bf[e] = (short)f2bf(frow[kt * 32 + e]);
      acc = __builtin_amdgcn_mfma_f32_16x16x32_bf16(a, bf, acc, 0, 0, 0);
    }
    int col = bk * 16 + n, r0 = (lane >> 4) * 4;
    float bias = fc_b[col];
#pragma unroll
    for (int rr = 0; rr < 4; rr++) {
      int b = wave * 16 + r0 + rr;
      hdec[(size_t)b * H + col] = f2bf(tanh_(acc[rr] + bias));
    }
  }
  gbar(bar, &dead, ++bc);
  // ---- time loop ----
  for (int t = 0; t < TD; t++) {
    const u16* hr = hdec + (t & 1) * (B * H);
    u16* hw = hdec + ((t + 1) & 1) * (B * H);
    // phase 1: full attention for batch b = bk (blocks 0..31)
    if (bk < 32) {
      const int b = bk;
      hs[tid] = bf2f(hr[b * H + tid]);
      hs[tid + 256] = bf2f(hr[b * H + 256 + tid]);
      __syncthreads();
      {  // hp = h @ a1^T : wave w covers k in [w*128, w*128+128), lane*8 j's
        float p[8] = {};
        const int j0 = lane * 8;
#pragma unroll 4
        for (int kk = 0; kk < 128; kk++) {
          int k = wave * 128 + kk;
          float hk = hs[k];
          u16x8 av = *(const u16x8*)&a1T_bf[(size_t)k * H + j0];
#pragma unroll
          for (int e = 0; e < 8; e++) p[e] += hk * bf2f(av[e]);
        }
#pragma unroll
        for (int e = 0; e < 8; e++) wsum[wave][j0 + e] = p[e];
      }
      __syncthreads();
      hps[tid] = wsum[0][tid] + wsum[1][tid] + wsum[2][tid] + wsum[3][tid];
      hps[tid + 256] =
          wsum[0][tid + 256] + wsum[1][tid + 256] + wsum[2][tid + 256] +
          wsum[3][tid + 256];
      __syncthreads();
      {  // scores
        const int j0 = lane * 8;
        float av8[8], hp8[8];
#pragma unroll
        for (int e = 0; e < 8; e++) {
          av8[e] = avs[j0 + e];
          hp8[e] = hps[j0 + e];
        }
        for (int i = 0; i < 32; i++) {
          int s = wave * 32 + i;
          u16x8 ep = *(const u16x8*)&epart_bf[((size_t)b * S + s) * H + j0];
          float a = 0.f;
#pragma unroll
          for (int e = 0; e < 8; e++) a += av8[e] * tanh_(hp8[e] + bf2f(ep[e]));
#pragma unroll
          for (int o = 32; o; o >>= 1) a += __shfl_xor(a, o);
          if (lane == 0) sc[s] = a;
        }
      }
      __syncthreads();
      if (tid < S && smask[tid] == PAD_IDX) sc[tid] = -1e10f;
      __syncthreads();
      if (tid < 64) {
        float v = fmaxf(sc[tid], sc[tid + 64]);
#pragma unroll
        for (int o = 32; o; o >>= 1) v = fmaxf(v, __shfl_xor(v, o));
        if (tid == 0) red[0] = v;
      }
      __syncthreads();
      float mx = red[0];
      if (tid < S) sc[tid] = __expf(sc[tid] - mx);
      __syncthreads();
      if (tid < 64) {
        float v = sc[tid] + sc[tid + 64];
#pragma unroll
        for (int o = 32; o; o >>= 1) v += __shfl_xor(v, o);
        if (tid == 0) red[1] = 1.f / v;
      }
      {  // weighted partials: wave w owns s in [w*32, w*32+32)
        float acc8[8] = {};
        const int j0 = lane * 8;
        for (int i = 0; i < 32; i++) {
          int s = wave * 32 + i;
          float pscale = sc[s];
          u16x8 ev = *(const u16x8*)&enc_bt_bf[((size_t)b * S + s) * H + j0];
#pragma unroll
          for (int e = 0; e < 8; e++) acc8[e] += pscale * bf2f(ev[e]);
        }
#pragma unroll
        for (int e = 0; e < 8; e++) wsum[wave][j0 + e] = acc8[e];
      }
      __syncthreads();
      {
        float inv = red[1];
#pragma unroll
        for (int rep = 0; rep < 2; rep++) {
          int j = rep * 256 + tid;
          float wj = (wsum[0][j] + wsum[1][j] + wsum[2][j] + wsum[3][j]) * inv;
          u16 wb = f2bf(wj);
          wbuf_bf[(size_t)b * H + j] = wb;
          xout_bf[((size_t)t * B + b) * KOUT + H + j] = wb;
        }
      }
    }
    gbar(bar, &dead, ++bc);
    // phase 2: dec LSTM (all 128 blocks)
    if (wave < 2) {
      int m = lane & 15, ks = lane >> 4, n = m;
      const u16* wb_ = wbuf_bf + (size_t)(wave * 16 + m) * H + ks * 8;
      const u16* hb = hr + (size_t)(wave * 16 + m) * H + ks * 8;
      f32x4 acc = {};
#pragma unroll
      for (int kt = 0; kt < 16; kt++) {
        bf16x8 a = *(const bf16x8*)(wb_ + kt * 32);
        bf16x8 w =
            *(const bf16x8*)&Ws[n * 1024 + (((kt * 4 + ks) ^ (n & 7)) << 3)];
        acc = __builtin_amdgcn_mfma_f32_16x16x32_bf16(a, w, acc, 0, 0, 0);
      }
#pragma unroll
      for (int kt = 0; kt < 16; kt++) {
        bf16x8 a = *(const bf16x8*)(hb + kt * 32);
        bf16x8 w = *(const bf16x8*)&Ws[n * 1024 +
                                       (((64 + kt * 4 + ks) ^ (n & 7)) << 3)];
        acc = __builtin_amdgcn_mfma_f32_16x16x32_bf16(a, w, acc, 0, 0, 0);
      }
      int r0 = ks * 4;
#pragma unroll
      for (int rr = 0; rr < 4; rr++) gs[wave * 16 + r0 + rr][n] = acc[rr];
    }
    __syncthreads();
    if (tid < 128) {
      int b = tid >> 2, q = tid & 3;
      float4 xv = *(const float4*)(eih_p + ((size_t)t * B + b) * H4 +
                                   (bk * 4 + q) * 4);
      float gi = xv.x + gs[b][q * 4 + 0];
      float gf = xv.y + gs[b][q * 4 + 1];
      float gg = xv.z + gs[b][q * 4 + 2];
      float go = xv.w + gs[b][q * 4 + 3];
      float cn = sigm(gf) * c_s[tid] + sigm(gi) * tanh_(gg);
      c_s[tid] = cn;
      float hn = sigm(go) * tanh_(cn);
      u16 h16 = f2bf(hn);
      hw[(size_t)b * H + bk * 4 + q] = h16;
      xout_bf[((size_t)t * B + b) * KOUT + bk * 4 + q] = h16;
    }
    gbar(bar, &dead, ++bc);
  }
}

// ---------------------------------------------------------------------------
extern "C" void kernel_launch(void* const* d_in, const int* in_sizes, int n_in,
                              void* d_out, int out_size, void* d_ws,
                              size_t ws_size, hipStream_t stream) {
  const int* src = (const int*)d_in[0];
  const int* trg = (const int*)d_in[2];
  const float* enc_emb = (const float*)d_in[3];
  const float* enc_wih = (const float*)d_in[4];
  const float* enc_whh = (const float*)d_in[5];
  const float* enc_bih = (const float*)d_in[6];
  const float* enc_bhh = (const float*)d_in[7];
  const float* fc_w = (const float*)d_in[8];
  const float* fc_b = (const float*)d_in[9];
  const float* dec_emb = (const float*)d_in[10];
  const float* attn_w = (const float*)d_in[11];
  const float* attn_b = (const float*)d_in[12];
  const float* attn_v = (const float*)d_in[13];
  const float* dec_wih = (const float*)d_in[14];
  const float* dec_whh = (const float*)d_in[15];
  const float* dec_bih = (const float*)d_in[16];
  const float* dec_bhh = (const float*)d_in[17];
  const float* out_w = (const float*)d_in[18];
  const float* out_b = (const float*)d_in[19];
  float* out = (float*)d_out;

  char* wp = (char*)d_ws;
  auto alloc = [&](size_t n) {
    char* p = wp;
    wp += (n + 255) & ~(size_t)255;
    return p;
  };
  u16* outw_bf = (u16*)alloc((size_t)V * KOUT * 2);      // 98.3 MB
  u16* wihenc_p = (u16*)alloc((size_t)H4 * H * 2);       // 2.1 MB
  u16* wihE_p = (u16*)alloc((size_t)H4 * H * 2);         // 2.1 MB
  u16* attnw2_bf = (u16*)alloc((size_t)H * H * 2);       // 0.5 MB
  u16* a1T_bf = (u16*)alloc((size_t)H * H * 2);          // 0.5 MB
  u16* xemb_bf = (u16*)alloc((size_t)S * B * H * 2);     // 4.2 MB
  float* xih_p = (float*)alloc((size_t)S * B * H4 * 4);  // 33.6 MB
  u16* enc_bt_bf = (u16*)alloc((size_t)B * S * H * 2);   // 4.2 MB
  u16* epart_bf = (u16*)alloc((size_t)B * S * H * 2);    // 4.2 MB
  float* eih_p = (float*)alloc((size_t)MOUT * H4 * 4);   // 16.5 MB
  u16* xout_bf = (u16*)alloc((size_t)MOUT * KOUT * 2);   // 6.2 MB
  u16* h_enc = (u16*)alloc((size_t)2 * B * H * 2);
  u16* hdec = (u16*)alloc((size_t)2 * B * H * 2);
  u16* wbuf_bf = (u16*)alloc((size_t)B * H * 2);
  float* cbuf = (float*)alloc((size_t)B * H * 4);
  float* benc_p = (float*)alloc((size_t)H4 * 4);
  float* bdec_p = (float*)alloc((size_t)H4 * 4);
  unsigned* bar_enc = (unsigned*)alloc(256);
  unsigned* bar_dec = (unsigned*)alloc(256);

  dim3 blk(256);
  zero_f<<<dim3(256), blk, 0, stream>>>(out, (long)B * V);
  zero_u<<<dim3(1), dim3(64), 0, stream>>>(bar_enc, 64);
  zero_u<<<dim3(1), dim3(64), 0, stream>>>(bar_dec, 64);
  // weight preparation
  cast_bf4<<<dim3(((long)V * KOUT / 4 + 255) / 256), blk, 0, stream>>>(
      out_w, outw_bf, (long)V * KOUT / 4);
  cast_perm<<<dim3(H / 256, H4), blk, 0, stream>>>(enc_wih, H, 0, wihenc_p);
  cast_perm<<<dim3(H / 256, H4), blk, 0, stream>>>(dec_wih, 2 * H, 0, wihE_p);
  cast_bf<<<dim3(H / 256, H), blk, 0, stream>>>(attn_w, attnw2_bf, 2 * H, H, H);
  cast_transpose_bf<<<dim3(H / 32, H / 32), blk, 0, stream>>>(attn_w, 2 * H, 0,
                                                              a1T_bf, H);
  bias_perm<<<dim3(H4 / 256), blk, 0, stream>>>(enc_bih, enc_bhh, benc_p);
  bias_perm<<<dim3(H4 / 256), blk, 0, stream>>>(dec_bih, dec_bhh, bdec_p);
  gather_src_emb<<<dim3(H / 256, S * B), blk, 0, stream>>>(src, enc_emb,
                                                           xemb_bf);
  gather_trg_emb<<<dim3(H / 256, MOUT), blk, 0, stream>>>(trg, dec_emb,
                                                          xout_bf);
  // input-side GEMMs (permuted cols)
  gemm_bt<<<dim3(H4 / 128, (S * B) / 128), blk, 0, stream>>>(
      xemb_bf, H, wihenc_p, H, xih_p, H4, benc_p, S * B, H, 0);
  gemm_bt<<<dim3(H4 / 128, (MOUT + 127) / 128), blk, 0, stream>>>(
      xout_bf + 2 * H, KOUT, wihE_p, H, eih_p, H4, bdec_p, MOUT, H, 0);
  // persistent encoder
  enc_persist<<<dim3(128), dim3(128), 0, stream>>>(bar_enc, enc_whh, xih_p,
                                                   h_enc, enc_bt_bf, cbuf);
  // epart = enc_bt @ attn_w2^T + attn_b  (bf16 out)
  gemm_bt<<<dim3(H / 128, (B * S) / 128), blk, 0, stream>>>(
      enc_bt_bf, H, attnw2_bf, H, (float*)epart_bf, H, attn_b, B * S, H, 1);
  // persistent decoder (h_f is in h_enc buffer 0 after S=128 steps)
  dec_persist<<<dim3(128), blk, 0, stream>>>(
      bar_dec, fc_w, fc_b, dec_wih, dec_whh, a1T_bf, attn_v, src, h_enc, cbuf,
      epart_bf, enc_bt_bf, eih_p, hdec, wbuf_bf, xout_bf);
  // final logits GEMM
  gemm_bt<<<dim3(V / 128, (MOUT + 127) / 128), blk, 0, stream>>>(
      xout_bf, KOUT, outw_bf, KOUT, out + (size_t)B * V, V, out_b, MOUT, KOUT,
      0);
}

// Round 5
// 3326.879 us; speedup vs baseline: 6.6497x; 1.8587x over previous
//
#include <hip/hip_runtime.h>

typedef unsigned short u16;
typedef unsigned int u32;
typedef unsigned long long u64;
typedef __attribute__((ext_vector_type(8))) short bf16x8;
typedef __attribute__((ext_vector_type(8))) unsigned short u16x8;
typedef __attribute__((ext_vector_type(4))) unsigned short u16x4;
typedef __attribute__((ext_vector_type(4))) float f32x4;

#define DEVI static __device__ __forceinline__

constexpr int B = 32, S = 128, T = 64, H = 512, V = 32000;
constexpr int H4 = 4 * H;          // 2048
constexpr int TD = T - 1;          // 63 decoder steps
constexpr int MOUT = TD * B;       // 2016
constexpr int KOUT = 3 * H;        // 1536
constexpr int PAD_IDX = 1;

DEVI u16 f2bf(float f) {
  union { float f; unsigned u; } v; v.f = f;
  unsigned r = (v.u + 0x7fffu + ((v.u >> 16) & 1u)) >> 16;
  return (u16)r;
}
DEVI float bf2f(u16 h) {
  union { unsigned u; float f; } v; v.u = ((unsigned)h) << 16;
  return v.f;
}
DEVI float sigm(float x) { return 1.f / (1.f + __expf(-x)); }
DEVI float tanh_(float x) {
  float ax = fabsf(x);
  float e = __expf(-2.f * ax);
  float t = (1.f - e) / (1.f + e);
  return x < 0.f ? -t : t;
}
DEVI float tanhf_(float x) {  // fast: correct at +-inf
  float e = __expf(2.f * x);
  return 1.f - 2.f * __builtin_amdgcn_rcpf(e + 1.f);
}
DEVI int swz(int row, int k8) { return row * 32 + ((k8 ^ (row & 3)) << 3); }

DEVI u64 pack4u(const u16* p) {
  return (u64)p[0] | ((u64)p[1] << 16) | ((u64)p[2] << 32) | ((u64)p[3] << 48);
}
DEVI u64 pack4f(float a, float b, float c, float d) {
  return (u64)f2bf(a) | ((u64)f2bf(b) << 16) | ((u64)f2bf(c) << 32) |
         ((u64)f2bf(d) << 48);
}
// write-through to coherence point; returned old value keeps vmcnt honest
DEVI u64 xstore(u16* p, u64 v) {
  return __hip_atomic_exchange((u64*)p, v, __ATOMIC_RELAXED,
                               __HIP_MEMORY_SCOPE_AGENT);
}
// relaxed flag wait: no cache-sweeping acquire
DEVI void flag_wait(unsigned* f, unsigned target, int* dead) {
  __syncthreads();
  if (threadIdx.x == 0 && !*dead) {
    long long t0 = (long long)__builtin_amdgcn_s_memrealtime();
    while (__hip_atomic_load(f, __ATOMIC_RELAXED,
                             __HIP_MEMORY_SCOPE_AGENT) < target) {
      __builtin_amdgcn_s_sleep(1);
      if ((long long)__builtin_amdgcn_s_memrealtime() - t0 > 20000000ll) {
        *dead = 1;
        break;
      }
    }
  }
  __syncthreads();
  asm volatile("" ::: "memory");
}

// ---------------- bf16 MFMA GEMM:  C[M,N] = A[M,K] * Bt[N,K]^T + bias ------
__global__ __launch_bounds__(256) void gemm_bt(
    const u16* __restrict__ A, int lda,
    const u16* __restrict__ Bt, int ldb,
    float* __restrict__ C, int ldc,
    const float* __restrict__ bias, int M, int K, int bf16out) {
  __shared__ u16 As[128 * 32], Bs[128 * 32];
  const int tid = threadIdx.x;
  const int m0 = blockIdx.y * 128, n0 = blockIdx.x * 128;
  const int lane = tid & 63, w = tid >> 6, wm = w >> 1, wn = w & 1;
  const int lr = lane & 15, lk = lane >> 4;
  f32x4 acc[4][4] = {};
  const int r = tid >> 1, cc = (tid & 1) * 16, k8b = (tid & 1) * 2;

  for (int k0 = 0; k0 < K; k0 += 32) {
    {
      long gr = m0 + r;
      u16x8 v0 = {}, v1 = {};
      if (gr < M) {
        const u16* s = A + gr * (long)lda + k0 + cc;
        v0 = *(const u16x8*)s;
        v1 = *(const u16x8*)(s + 8);
      }
      *(u16x8*)&As[swz(r, k8b)] = v0;
      *(u16x8*)&As[swz(r, k8b + 1)] = v1;
    }
    {
      const u16* s = Bt + (long)(n0 + r) * ldb + k0 + cc;
      u16x8 v0 = *(const u16x8*)s;
      u16x8 v1 = *(const u16x8*)(s + 8);
      *(u16x8*)&Bs[swz(r, k8b)] = v0;
      *(u16x8*)&Bs[swz(r, k8b + 1)] = v1;
    }
    __syncthreads();
    bf16x8 af[4], bfr[4];
#pragma unroll
    for (int mi = 0; mi < 4; mi++)
      af[mi] = *(const bf16x8*)&As[swz(wm * 64 + mi * 16 + lr, lk)];
#pragma unroll
    for (int ni = 0; ni < 4; ni++)
      bfr[ni] = *(const bf16x8*)&Bs[swz(wn * 64 + ni * 16 + lr, lk)];
#pragma unroll
    for (int mi = 0; mi < 4; mi++)
#pragma unroll
      for (int ni = 0; ni < 4; ni++)
        acc[mi][ni] = __builtin_amdgcn_mfma_f32_16x16x32_bf16(
            af[mi], bfr[ni], acc[mi][ni], 0, 0, 0);
    __syncthreads();
  }
#pragma unroll
  for (int ni = 0; ni < 4; ni++) {
    int col = n0 + wn * 64 + ni * 16 + lr;
    float bs = bias ? bias[col] : 0.f;
#pragma unroll
    for (int mi = 0; mi < 4; mi++) {
#pragma unroll
      for (int rr = 0; rr < 4; rr++) {
        long row = m0 + wm * 64 + mi * 16 + lk * 4 + rr;
        if (row < M) {
          float v = acc[mi][ni][rr] + bs;
          if (bf16out)
            ((u16*)C)[row * (long)ldc + col] = f2bf(v);
          else
            C[row * (long)ldc + col] = v;
        }
      }
    }
  }
}

// ---------------- helpers ---------------------------------------------------
__global__ void zero_f(float* p, long n) {
  long i = (long)blockIdx.x * 256 + threadIdx.x;
  long st = (long)gridDim.x * 256;
  for (; i < n; i += st) p[i] = 0.f;
}

__global__ void zero_u(unsigned* p, int n) {
  int i = blockIdx.x * 256 + threadIdx.x;
  if (i < n) p[i] = 0u;
}

__global__ void cast_bf(const float* __restrict__ src, u16* __restrict__ dst,
                        int ld, int off, int Csz) {
  long row = blockIdx.y;
  int col = blockIdx.x * 256 + threadIdx.x;
  dst[row * Csz + col] = f2bf(src[row * ld + off + col]);
}

__global__ void cast_bf4(const float* __restrict__ src, u16* __restrict__ dst,
                         long n4) {
  long i = (long)blockIdx.x * 256 + threadIdx.x;
  if (i >= n4) return;
  float4 v = ((const float4*)src)[i];
  u16x4 o;
  o[0] = f2bf(v.x); o[1] = f2bf(v.y); o[2] = f2bf(v.z); o[3] = f2bf(v.w);
  *(u16x4*)&dst[i * 4] = o;
}

// permuted-row cast: dst row n' = src row (g*H + jH), n' = jH*4 + g
__global__ void cast_perm(const float* __restrict__ src, int ld, int off,
                          u16* __restrict__ dst) {
  int np = blockIdx.y;
  int c = blockIdx.x * 256 + threadIdx.x;
  int g = np & 3, jH = np >> 2;
  dst[(size_t)np * H + c] = f2bf(src[(size_t)(g * H + jH) * ld + off + c]);
}

__global__ void bias_perm(const float* __restrict__ a,
                          const float* __restrict__ b, float* __restrict__ o) {
  int np = blockIdx.x * 256 + threadIdx.x;
  int g = np & 3, jH = np >> 2;
  int r = g * H + jH;
  o[np] = a[r] + b[r];
}

// dst[c*R + r] = bf16(src[r*ld + off + c]); grid (C/32, R/32)
__global__ __launch_bounds__(256) void cast_transpose_bf(
    const float* __restrict__ src, int ld, int off, u16* __restrict__ dst,
    int R) {
  __shared__ float tile[32][33];
  int r0 = blockIdx.y * 32, c0 = blockIdx.x * 32;
  int tx = threadIdx.x & 31, ty = threadIdx.x >> 5;
#pragma unroll
  for (int i = 0; i < 32; i += 8)
    tile[ty + i][tx] = src[(long)(r0 + ty + i) * ld + off + c0 + tx];
  __syncthreads();
#pragma unroll
  for (int i = 0; i < 32; i += 8)
    dst[(long)(c0 + ty + i) * R + r0 + tx] = f2bf(tile[tx][ty + i]);
}

__global__ void gather_src_emb(const int* __restrict__ src,
                               const float* __restrict__ emb,
                               u16* __restrict__ dst) {
  int row = blockIdx.y;           // row = t*B + b
  int t = row >> 5, b = row & 31;
  int c = blockIdx.x * 256 + threadIdx.x;
  int tok = src[b * S + t];
  dst[(long)row * H + c] = f2bf(emb[(long)tok * H + c]);
}

__global__ void gather_trg_emb(const int* __restrict__ trg,
                               const float* __restrict__ emb,
                               u16* __restrict__ xout) {
  int row = blockIdx.y;           // row = t*B + b, t < 63
  int t = row >> 5, b = row & 31;
  int c = blockIdx.x * 256 + threadIdx.x;
  int tok = trg[b * T + t];
  xout[(long)row * KOUT + 2 * H + c] = f2bf(emb[(long)tok * H + c]);
}

// ---------------- persistent encoder ----------------------------------------
// 128 blocks x 128 threads. Block bk owns cols [bk*4, bk*4+4) for all gates.
// hstep: (S+1) step buffers of [B][H] bf16, monotonic; fe[t] counts h[t] ready.
__global__ __launch_bounds__(128) void enc_persist(
    unsigned* fe, const float* __restrict__ whh,
    const float* __restrict__ xih_p, u16* hstep, u16* enc_bt_bf, float* cbuf) {
  const int tid = threadIdx.x, bk = blockIdx.x;
  const int wave = tid >> 6, lane = tid & 63;
  __shared__ float gs[32][16];
  __shared__ float c_s[128];
  __shared__ u16 hx[128];
  __shared__ int dead;
  if (tid == 0) dead = 0;
  // B-frag preload: lane n=lane&15 -> (g=n&3,q=n>>2); k = kt*32+(lane>>4)*8+e
  bf16x8 wf[16];
  {
    int n = lane & 15, g = n & 3, q = n >> 2;
    const float* wrow =
        whh + ((size_t)g * H + bk * 4 + q) * H + (lane >> 4) * 8;
#pragma unroll
    for (int kt = 0; kt < 16; kt++) {
      bf16x8 f;
#pragma unroll
      for (int e = 0; e < 8; e++) f[e] = (short)f2bf(wrow[kt * 32 + e]);
      wf[kt] = f;
    }
  }
  c_s[tid] = 0.f;
  for (int t = 0; t < S; t++) {
    if (t > 0) flag_wait(fe + t, 128, &dead);
    // gate input (independent of h) hoisted ahead of MFMA
    float4 xv = *(const float4*)(xih_p + ((size_t)t * B + (tid >> 2)) * H4 +
                                 (bk * 4 + (tid & 3)) * 4);
    if (t > 0) {
      const u16* hb = hstep + (size_t)t * B * H +
                      (size_t)(wave * 16 + (lane & 15)) * H + (lane >> 4) * 8;
      f32x4 acc = {};
#pragma unroll
      for (int kt = 0; kt < 16; kt++) {
        bf16x8 a = *(const bf16x8*)(hb + kt * 32);
        acc = __builtin_amdgcn_mfma_f32_16x16x32_bf16(a, wf[kt], acc, 0, 0, 0);
      }
      int n = lane & 15, r0 = (lane >> 4) * 4;
#pragma unroll
      for (int rr = 0; rr < 4; rr++) gs[wave * 16 + r0 + rr][n] = acc[rr];
    } else {
      int n = lane & 15, r0 = (lane >> 4) * 4;
#pragma unroll
      for (int rr = 0; rr < 4; rr++) gs[wave * 16 + r0 + rr][n] = 0.f;
    }
    __syncthreads();
    {
      int b = tid >> 2, q = tid & 3;
      float gi = xv.x + gs[b][q * 4 + 0];
      float gf = xv.y + gs[b][q * 4 + 1];
      float gg = xv.z + gs[b][q * 4 + 2];
      float go = xv.w + gs[b][q * 4 + 3];
      float cn = sigm(gf) * c_s[tid] + sigm(gi) * tanh_(gg);
      c_s[tid] = cn;
      float hn = sigm(go) * tanh_(cn);
      u16 h16 = f2bf(hn);
      hx[tid] = h16;
      enc_bt_bf[((size_t)b * S + t) * H + bk * 4 + q] = h16;  // normal store
    }
    __syncthreads();
    u64 kp = 0;
    if (tid < 32)
      kp = xstore(hstep + (size_t)(t + 1) * B * H + (size_t)tid * H + bk * 4,
                  pack4u(&hx[tid * 4]));
    if (wave == 0) {
      asm volatile("" :: "v"(kp));
      asm volatile("s_waitcnt vmcnt(0)" ::: "memory");
      if (tid == 0)
        __hip_atomic_fetch_add(fe + t + 1, 1u, __ATOMIC_RELAXED,
                               __HIP_MEMORY_SCOPE_AGENT);
    }
  }
  {
    int b = tid >> 2, q = tid & 3;
    cbuf[b * H + bk * 4 + q] = c_s[tid];  // kernel-boundary consumer
  }
}

// ---------------- persistent decoder ----------------------------------------
// 128 blocks x 256 threads. fh[t] (128; fh[0]=32) = h[t] ready, fw[t] (32)
// = weighted[t] ready. hstep/wstep monotonic per-step [B][H] bf16 buffers.
__global__ __launch_bounds__(256) void dec_persist(
    unsigned* fh, unsigned* fw, const float* __restrict__ fc_w,
    const float* __restrict__ fc_b, const float* __restrict__ dec_wih,
    const float* __restrict__ dec_whh, const u16* __restrict__ a1T_bf,
    const float* __restrict__ attn_v, const int* __restrict__ src,
    const u16* __restrict__ hf_bf, const float* __restrict__ cbuf,
    const u16* __restrict__ epart_bf, const u16* __restrict__ enc_bt_bf,
    const float* __restrict__ eih_p, u16* hstep, u16* wstep,
    u16* __restrict__ xout_bf) {
  const int tid = threadIdx.x, bk = blockIdx.x;
  const int wave = tid >> 6, lane = tid & 63;
  __shared__ u16 Ws[16 * 1024];     // LSTM weights, XOR-swizzled
  __shared__ float gs[32][16];
  __shared__ float c_s[128];
  __shared__ float hs[H], hps[H], avs[H], wsum[4][H], sc[S], red[2];
  __shared__ int smask[S];
  __shared__ u16 wtmp[H];
  __shared__ u16 hx[128];
  __shared__ int dead;
  if (tid == 0) dead = 0;
  // ---- prologue: LSTM weights -> LDS ----
  for (int idx = tid; idx < 16 * 1024; idx += 256) {
    int n = idx >> 10, k = idx & 1023;
    int g = n & 3, q = n >> 2;
    int grow = g * H + bk * 4 + q;
    float v = (k < 512) ? dec_wih[(size_t)grow * (2 * H) + 512 + k]
                        : dec_whh[(size_t)grow * H + (k - 512)];
    Ws[n * 1024 + (((k >> 3) ^ (n & 7)) << 3) + (k & 7)] = f2bf(v);
  }
  if (tid < 128) c_s[tid] = cbuf[(tid >> 2) * H + bk * 4 + (tid & 3)];
  if (bk < 32) {
    avs[tid] = attn_v[tid];
    avs[tid + 256] = attn_v[tid + 256];
    if (tid < S) smask[tid] = src[bk * S + tid];
  }
  // fc: hidden = tanh(hf @ fc_w^T + fc_b) -> h[0]  (blocks 0..31, 16 cols each)
  if (bk < 32 && wave < 2) {
    int n = lane & 15;
    const u16* hb = hf_bf + (size_t)(wave * 16 + n) * H + (lane >> 4) * 8;
    const float* frow = fc_w + (size_t)(bk * 16 + n) * H + (lane >> 4) * 8;
    f32x4 acc = {};
#pragma unroll
    for (int kt = 0; kt < 16; kt++) {
      bf16x8 a = *(const bf16x8*)(hb + kt * 32);
      bf16x8 bf;
#pragma unroll
      for (int e = 0; e < 8; e++) bf[e] = (short)f2bf(frow[kt * 32 + e]);
      acc = __builtin_amdgcn_mfma_f32_16x16x32_bf16(a, bf, acc, 0, 0, 0);
    }
    float bias = fc_b[bk * 16 + n];
    int r0 = (lane >> 4) * 4;
#pragma unroll
    for (int rr = 0; rr < 4; rr++)
      gs[wave * 16 + r0 + rr][n] = tanh_(acc[rr] + bias);
  }
  __syncthreads();
  {
    u64 kp = 0;
    if (bk < 32 && tid < 64) {
#pragma unroll
      for (int uu = 0; uu < 2; uu++) {
        int u = tid * 2 + uu;       // u64 index: b = u>>2, qq = u&3
        int b = u >> 2, qq = u & 3;
        u64 val = pack4f(gs[b][qq * 4], gs[b][qq * 4 + 1], gs[b][qq * 4 + 2],
                         gs[b][qq * 4 + 3]);
        kp ^= xstore(hstep + (size_t)b * H + bk * 16 + qq * 4, val);
      }
    }
    if (bk < 32 && wave == 0) {
      asm volatile("" :: "v"(kp));
      asm volatile("s_waitcnt vmcnt(0)" ::: "memory");
      if (tid == 0)
        __hip_atomic_fetch_add(fh, 1u, __ATOMIC_RELAXED,
                               __HIP_MEMORY_SCOPE_AGENT);
    }
  }
  // ---- time loop ----
  for (int t = 0; t < TD; t++) {
    // phase 1: attention for batch b = bk (blocks 0..31)
    if (bk < 32) {
      flag_wait(fh + t, t == 0 ? 32u : 128u, &dead);
      const int b = bk;
      {  // load h row (fresh-from-LLC, cold address)
        u32 v = ((const u32*)(hstep + (size_t)t * B * H + (size_t)b * H))[tid];
        hs[2 * tid] = bf2f((u16)(v & 0xffff));
        hs[2 * tid + 1] = bf2f((u16)(v >> 16));
      }
      __syncthreads();
      {  // hp = h @ a1^T : wave w covers k in [w*128, w*128+128)
        float p[8] = {};
        const int j0 = lane * 8;
#pragma unroll 4
        for (int kk = 0; kk < 128; kk++) {
          int k = wave * 128 + kk;
          float hk = hs[k];
          u16x8 av = *(const u16x8*)&a1T_bf[(size_t)k * H + j0];
#pragma unroll
          for (int e = 0; e < 8; e++) p[e] += hk * bf2f(av[e]);
        }
#pragma unroll
        for (int e = 0; e < 8; e++) wsum[wave][j0 + e] = p[e];
      }
      __syncthreads();
      hps[tid] = wsum[0][tid] + wsum[1][tid] + wsum[2][tid] + wsum[3][tid];
      hps[tid + 256] = wsum[0][tid + 256] + wsum[1][tid + 256] +
                       wsum[2][tid + 256] + wsum[3][tid + 256];
      __syncthreads();
      {  // scores
        const int j0 = lane * 8;
        float av8[8], hp8[8];
#pragma unroll
        for (int e = 0; e < 8; e++) {
          av8[e] = avs[j0 + e];
          hp8[e] = hps[j0 + e];
        }
        for (int i = 0; i < 32; i++) {
          int s = wave * 32 + i;
          u16x8 ep = *(const u16x8*)&epart_bf[((size_t)b * S + s) * H + j0];
          float a = 0.f;
#pragma unroll
          for (int e = 0; e < 8; e++)
            a += av8[e] * tanhf_(hp8[e] + bf2f(ep[e]));
#pragma unroll
          for (int o = 32; o; o >>= 1) a += __shfl_xor(a, o);
          if (lane == 0) sc[s] = a;
        }
      }
      __syncthreads();
      if (tid < S && smask[tid] == PAD_IDX) sc[tid] = -1e10f;
      __syncthreads();
      if (tid < 64) {
        float v = fmaxf(sc[tid], sc[tid + 64]);
#pragma unroll
        for (int o = 32; o; o >>= 1) v = fmaxf(v, __shfl_xor(v, o));
        if (tid == 0) red[0] = v;
      }
      __syncthreads();
      float mx = red[0];
      if (tid < S) sc[tid] = __expf(sc[tid] - mx);
      __syncthreads();
      if (tid < 64) {
        float v = sc[tid] + sc[tid + 64];
#pragma unroll
        for (int o = 32; o; o >>= 1) v += __shfl_xor(v, o);
        if (tid == 0) red[1] = 1.f / v;
      }
      {  // weighted partials: wave w owns s in [w*32, w*32+32)
        float acc8[8] = {};
        const int j0 = lane * 8;
        for (int i = 0; i < 32; i++) {
          int s = wave * 32 + i;
          float pscale = sc[s];
          u16x8 ev = *(const u16x8*)&enc_bt_bf[((size_t)b * S + s) * H + j0];
#pragma unroll
          for (int e = 0; e < 8; e++) acc8[e] += pscale * bf2f(ev[e]);
        }
#pragma unroll
        for (int e = 0; e < 8; e++) wsum[wave][j0 + e] = acc8[e];
      }
      __syncthreads();
      {
        float inv = red[1];
#pragma unroll
        for (int rep = 0; rep < 2; rep++) {
          int j = rep * 256 + tid;
          float wj = (wsum[0][j] + wsum[1][j] + wsum[2][j] + wsum[3][j]) * inv;
          u16 wb = f2bf(wj);
          wtmp[j] = wb;
          xout_bf[((size_t)t * B + b) * KOUT + H + j] = wb;  // normal store
        }
      }
      __syncthreads();
      u64 kp = 0;
      if (tid < 64) {
        int j0 = tid * 8;
        kp = xstore(wstep + (size_t)t * B * H + (size_t)b * H + j0,
                    pack4u(&wtmp[j0]));
        kp ^= xstore(wstep + (size_t)t * B * H + (size_t)b * H + j0 + 4,
                     pack4u(&wtmp[j0 + 4]));
      }
      if (wave == 0) {
        asm volatile("" :: "v"(kp));
        asm volatile("s_waitcnt vmcnt(0)" ::: "memory");
        if (tid == 0)
          __hip_atomic_fetch_add(fw + t, 1u, __ATOMIC_RELAXED,
                                 __HIP_MEMORY_SCOPE_AGENT);
      }
    }
    // phase 2: dec LSTM (all 128 blocks)
    flag_wait(fw + t, 32u, &dead);
    if (wave < 2) {
      int m = lane & 15, ks = lane >> 4, n = m;
      const u16* wb_ =
          wstep + (size_t)t * B * H + (size_t)(wave * 16 + m) * H + ks * 8;
      const u16* hb =
          hstep + (size_t)t * B * H + (size_t)(wave * 16 + m) * H + ks * 8;
      f32x4 acc = {};
#pragma unroll
      for (int kt = 0; kt < 16; kt++) {
        bf16x8 a = *(const bf16x8*)(wb_ + kt * 32);
        bf16x8 w =
            *(const bf16x8*)&Ws[n * 1024 + (((kt * 4 + ks) ^ (n & 7)) << 3)];
        acc = __builtin_amdgcn_mfma_f32_16x16x32_bf16(a, w, acc, 0, 0, 0);
      }
#pragma unroll
      for (int kt = 0; kt < 16; kt++) {
        bf16x8 a = *(const bf16x8*)(hb + kt * 32);
        bf16x8 w = *(const bf16x8*)&Ws[n * 1024 +
                                       (((64 + kt * 4 + ks) ^ (n & 7)) << 3)];
        acc = __builtin_amdgcn_mfma_f32_16x16x32_bf16(a, w, acc, 0, 0, 0);
      }
      int r0 = ks * 4;
#pragma unroll
      for (int rr = 0; rr < 4; rr++) gs[wave * 16 + r0 + rr][n] = acc[rr];
    }
    __syncthreads();
    if (tid < 128) {
      int b = tid >> 2, q = tid & 3;
      float4 xv = *(const float4*)(eih_p + ((size_t)t * B + b) * H4 +
                                   (bk * 4 + q) * 4);
      float gi = xv.x + gs[b][q * 4 + 0];
      float gf = xv.y + gs[b][q * 4 + 1];
      float gg = xv.z + gs[b][q * 4 + 2];
      float go = xv.w + gs[b][q * 4 + 3];
      float cn = sigm(gf) * c_s[tid] + sigm(gi) * tanh_(gg);
      c_s[tid] = cn;
      float hn = sigm(go) * tanh_(cn);
      u16 h16 = f2bf(hn);
      hx[tid] = h16;
      xout_bf[((size_t)t * B + b) * KOUT + bk * 4 + q] = h16;  // normal store
    }
    __syncthreads();
    u64 kp = 0;
    if (tid < 32)
      kp = xstore(hstep + (size_t)(t + 1) * B * H + (size_t)tid * H + bk * 4,
                  pack4u(&hx[tid * 4]));
    if (wave == 0) {
      asm volatile("" :: "v"(kp));
      asm volatile("s_waitcnt vmcnt(0)" ::: "memory");
      if (tid == 0)
        __hip_atomic_fetch_add(fh + t + 1, 1u, __ATOMIC_RELAXED,
                               __HIP_MEMORY_SCOPE_AGENT);
    }
  }
}

// ---------------------------------------------------------------------------
extern "C" void kernel_launch(void* const* d_in, const int* in_sizes, int n_in,
                              void* d_out, int out_size, void* d_ws,
                              size_t ws_size, hipStream_t stream) {
  const int* src = (const int*)d_in[0];
  const int* trg = (const int*)d_in[2];
  const float* enc_emb = (const float*)d_in[3];
  const float* enc_wih = (const float*)d_in[4];
  const float* enc_whh = (const float*)d_in[5];
  const float* enc_bih = (const float*)d_in[6];
  const float* enc_bhh = (const float*)d_in[7];
  const float* fc_w = (const float*)d_in[8];
  const float* fc_b = (const float*)d_in[9];
  const float* dec_emb = (const float*)d_in[10];
  const float* attn_w = (const float*)d_in[11];
  const float* attn_b = (const float*)d_in[12];
  const float* attn_v = (const float*)d_in[13];
  const float* dec_wih = (const float*)d_in[14];
  const float* dec_whh = (const float*)d_in[15];
  const float* dec_bih = (const float*)d_in[16];
  const float* dec_bhh = (const float*)d_in[17];
  const float* out_w = (const float*)d_in[18];
  const float* out_b = (const float*)d_in[19];
  float* out = (float*)d_out;

  char* wp = (char*)d_ws;
  auto alloc = [&](size_t n) {
    char* p = wp;
    wp += (n + 255) & ~(size_t)255;
    return p;
  };
  u16* outw_bf = (u16*)alloc((size_t)V * KOUT * 2);        // 98.3 MB
  u16* wihenc_p = (u16*)alloc((size_t)H4 * H * 2);         // 2.1 MB
  u16* wihE_p = (u16*)alloc((size_t)H4 * H * 2);           // 2.1 MB
  u16* attnw2_bf = (u16*)alloc((size_t)H * H * 2);         // 0.5 MB
  u16* a1T_bf = (u16*)alloc((size_t)H * H * 2);            // 0.5 MB
  u16* xemb_bf = (u16*)alloc((size_t)S * B * H * 2);       // 4.2 MB
  float* xih_p = (float*)alloc((size_t)S * B * H4 * 4);    // 33.6 MB
  u16* enc_bt_bf = (u16*)alloc((size_t)B * S * H * 2);     // 4.2 MB
  u16* epart_bf = (u16*)alloc((size_t)B * S * H * 2);      // 4.2 MB
  float* eih_p = (float*)alloc((size_t)MOUT * H4 * 4);     // 16.5 MB
  u16* xout_bf = (u16*)alloc((size_t)MOUT * KOUT * 2);     // 6.2 MB
  u16* hstep_enc = (u16*)alloc((size_t)(S + 1) * B * H * 2);  // 4.3 MB
  u16* hstep_dec = (u16*)alloc((size_t)T * B * H * 2);        // 2.1 MB
  u16* wstep = (u16*)alloc((size_t)TD * B * H * 2);           // 2.1 MB
  float* cbuf = (float*)alloc((size_t)B * H * 4);
  float* benc_p = (float*)alloc((size_t)H4 * 4);
  float* bdec_p = (float*)alloc((size_t)H4 * 4);
  unsigned* flags = (unsigned*)alloc(512 * 4);
  unsigned* fe = flags;          // [0..128], target 128
  unsigned* fh = flags + 256;    // [0..63], fh[0] target 32, else 128
  unsigned* fw = flags + 320;    // [0..62], target 32

  dim3 blk(256);
  zero_f<<<dim3(256), blk, 0, stream>>>(out, (long)B * V);
  zero_u<<<dim3(2), blk, 0, stream>>>(flags, 512);
  // weight preparation
  cast_bf4<<<dim3(((long)V * KOUT / 4 + 255) / 256), blk, 0, stream>>>(
      out_w, outw_bf, (long)V * KOUT / 4);
  cast_perm<<<dim3(H / 256, H4), blk, 0, stream>>>(enc_wih, H, 0, wihenc_p);
  cast_perm<<<dim3(H / 256, H4), blk, 0, stream>>>(dec_wih, 2 * H, 0, wihE_p);
  cast_bf<<<dim3(H / 256, H), blk, 0, stream>>>(attn_w, attnw2_bf, 2 * H, H, H);
  cast_transpose_bf<<<dim3(H / 32, H / 32), blk, 0, stream>>>(attn_w, 2 * H, 0,
                                                              a1T_bf, H);
  bias_perm<<<dim3(H4 / 256), blk, 0, stream>>>(enc_bih, enc_bhh, benc_p);
  bias_perm<<<dim3(H4 / 256), blk, 0, stream>>>(dec_bih, dec_bhh, bdec_p);
  gather_src_emb<<<dim3(H / 256, S * B), blk, 0, stream>>>(src, enc_emb,
                                                           xemb_bf);
  gather_trg_emb<<<dim3(H / 256, MOUT), blk, 0, stream>>>(trg, dec_emb,
                                                          xout_bf);
  // input-side GEMMs (permuted cols)
  gemm_bt<<<dim3(H4 / 128, (S * B) / 128), blk, 0, stream>>>(
      xemb_bf, H, wihenc_p, H, xih_p, H4, benc_p, S * B, H, 0);
  gemm_bt<<<dim3(H4 / 128, (MOUT + 127) / 128), blk, 0, stream>>>(
      xout_bf + 2 * H, KOUT, wihE_p, H, eih_p, H4, bdec_p, MOUT, H, 0);
  // persistent encoder
  enc_persist<<<dim3(128), dim3(128), 0, stream>>>(fe, enc_whh, xih_p,
                                                   hstep_enc, enc_bt_bf, cbuf);
  // epart = enc_bt @ attn_w2^T + attn_b  (bf16 out)
  gemm_bt<<<dim3(H / 128, (B * S) / 128), blk, 0, stream>>>(
      enc_bt_bf, H, attnw2_bf, H, (float*)epart_bf, H, attn_b, B * S, H, 1);
  // persistent decoder (h_f = hstep_enc step S)
  dec_persist<<<dim3(128), blk, 0, stream>>>(
      fh, fw, fc_w, fc_b, dec_wih, dec_whh, a1T_bf, attn_v, src,
      hstep_enc + (size_t)S * B * H, cbuf, epart_bf, enc_bt_bf, eih_p,
      hstep_dec, wstep, xout_bf);
  // final logits GEMM
  gemm_bt<<<dim3(V / 128, (MOUT + 127) / 128), blk, 0, stream>>>(
      xout_bf, KOUT, outw_bf, KOUT, out + (size_t)B * V, V, out_b, MOUT, KOUT,
      0);
}

// Round 6
// 2622.877 us; speedup vs baseline: 8.4346x; 1.2684x over previous
//
#include <hip/hip_runtime.h>

typedef unsigned short u16;
typedef unsigned int u32;
typedef unsigned long long u64;
typedef __attribute__((ext_vector_type(8))) short bf16x8;
typedef __attribute__((ext_vector_type(8))) unsigned short u16x8;
typedef __attribute__((ext_vector_type(4))) unsigned short u16x4;
typedef __attribute__((ext_vector_type(4))) float f32x4;

#define DEVI static __device__ __forceinline__

constexpr int B = 32, S = 128, T = 64, H = 512, V = 32000;
constexpr int H4 = 4 * H;          // 2048
constexpr int TD = T - 1;          // 63 decoder steps
constexpr int MOUT = TD * B;       // 2016
constexpr int KOUT = 3 * H;        // 1536
constexpr int PAD_IDX = 1;

DEVI u16 f2bf(float f) {
  union { float f; unsigned u; } v; v.f = f;
  unsigned r = (v.u + 0x7fffu + ((v.u >> 16) & 1u)) >> 16;
  return (u16)r;
}
DEVI float bf2f(u16 h) {
  union { unsigned u; float f; } v; v.u = ((unsigned)h) << 16;
  return v.f;
}
DEVI float sigm(float x) { return 1.f / (1.f + __expf(-x)); }
DEVI float tanh_(float x) {
  float ax = fabsf(x);
  float e = __expf(-2.f * ax);
  float t = (1.f - e) / (1.f + e);
  return x < 0.f ? -t : t;
}
DEVI float tanhf_(float x) {
  float e = __expf(2.f * x);
  return 1.f - 2.f * __builtin_amdgcn_rcpf(e + 1.f);
}
DEVI int swz(int row, int k8) { return row * 32 + ((k8 ^ (row & 3)) << 3); }

DEVI u64 pack4u(const u16* p) {
  return (u64)p[0] | ((u64)p[1] << 16) | ((u64)p[2] << 32) | ((u64)p[3] << 48);
}
// data write-through to coherence point; returned old keeps vmcnt honest
DEVI u64 xstore(u16* p, u64 v) {
  return __hip_atomic_exchange((u64*)p, v, __ATOMIC_RELAXED,
                               __HIP_MEMORY_SCOPE_AGENT);
}
// slot publish: absolute value, fire-and-forget
DEVI void sstore(unsigned* p, unsigned v) {
  __hip_atomic_exchange(p, v, __ATOMIC_RELAXED, __HIP_MEMORY_SCOPE_AGENT);
}
// per-thread slot poll (loads only; 64B-strided slots -> no line contention)
DEVI void poll_slot(unsigned* p, unsigned tgt) {
  long long t0 = (long long)__builtin_amdgcn_s_memrealtime();
  while (__hip_atomic_load(p, __ATOMIC_RELAXED, __HIP_MEMORY_SCOPE_AGENT) <
         tgt) {
    __builtin_amdgcn_s_sleep(1);
    if ((long long)__builtin_amdgcn_s_memrealtime() - t0 > 20000000ll) break;
  }
}

// ---------------- bf16 MFMA GEMM:  C[M,N] = A[M,K] * Bt[N,K]^T + bias ------
__global__ __launch_bounds__(256) void gemm_bt(
    const u16* __restrict__ A, int lda,
    const u16* __restrict__ Bt, int ldb,
    float* __restrict__ C, int ldc,
    const float* __restrict__ bias, int M, int K, int bf16out) {
  __shared__ u16 As[128 * 32], Bs[128 * 32];
  const int tid = threadIdx.x;
  const int m0 = blockIdx.y * 128, n0 = blockIdx.x * 128;
  const int lane = tid & 63, w = tid >> 6, wm = w >> 1, wn = w & 1;
  const int lr = lane & 15, lk = lane >> 4;
  f32x4 acc[4][4] = {};
  const int r = tid >> 1, cc = (tid & 1) * 16, k8b = (tid & 1) * 2;

  for (int k0 = 0; k0 < K; k0 += 32) {
    {
      long gr = m0 + r;
      u16x8 v0 = {}, v1 = {};
      if (gr < M) {
        const u16* s = A + gr * (long)lda + k0 + cc;
        v0 = *(const u16x8*)s;
        v1 = *(const u16x8*)(s + 8);
      }
      *(u16x8*)&As[swz(r, k8b)] = v0;
      *(u16x8*)&As[swz(r, k8b + 1)] = v1;
    }
    {
      const u16* s = Bt + (long)(n0 + r) * ldb + k0 + cc;
      u16x8 v0 = *(const u16x8*)s;
      u16x8 v1 = *(const u16x8*)(s + 8);
      *(u16x8*)&Bs[swz(r, k8b)] = v0;
      *(u16x8*)&Bs[swz(r, k8b + 1)] = v1;
    }
    __syncthreads();
    bf16x8 af[4], bfr[4];
#pragma unroll
    for (int mi = 0; mi < 4; mi++)
      af[mi] = *(const bf16x8*)&As[swz(wm * 64 + mi * 16 + lr, lk)];
#pragma unroll
    for (int ni = 0; ni < 4; ni++)
      bfr[ni] = *(const bf16x8*)&Bs[swz(wn * 64 + ni * 16 + lr, lk)];
#pragma unroll
    for (int mi = 0; mi < 4; mi++)
#pragma unroll
      for (int ni = 0; ni < 4; ni++)
        acc[mi][ni] = __builtin_amdgcn_mfma_f32_16x16x32_bf16(
            af[mi], bfr[ni], acc[mi][ni], 0, 0, 0);
    __syncthreads();
  }
#pragma unroll
  for (int ni = 0; ni < 4; ni++) {
    int col = n0 + wn * 64 + ni * 16 + lr;
    float bs = bias ? bias[col] : 0.f;
#pragma unroll
    for (int mi = 0; mi < 4; mi++) {
#pragma unroll
      for (int rr = 0; rr < 4; rr++) {
        long row = m0 + wm * 64 + mi * 16 + lk * 4 + rr;
        if (row < M) {
          float v = acc[mi][ni][rr] + bs;
          if (bf16out)
            ((u16*)C)[row * (long)ldc + col] = f2bf(v);
          else
            C[row * (long)ldc + col] = v;
        }
      }
    }
  }
}

// ---------------- helpers ---------------------------------------------------
__global__ void zero_f(float* p, long n) {
  long i = (long)blockIdx.x * 256 + threadIdx.x;
  long st = (long)gridDim.x * 256;
  for (; i < n; i += st) p[i] = 0.f;
}

__global__ void zero_u(unsigned* p, int n) {
  int i = blockIdx.x * 256 + threadIdx.x;
  if (i < n) p[i] = 0u;
}

__global__ void cast_bf(const float* __restrict__ src, u16* __restrict__ dst,
                        int ld, int off, int Csz) {
  long row = blockIdx.y;
  int col = blockIdx.x * 256 + threadIdx.x;
  dst[row * Csz + col] = f2bf(src[row * ld + off + col]);
}

__global__ void cast_bf4(const float* __restrict__ src, u16* __restrict__ dst,
                         long n4) {
  long i = (long)blockIdx.x * 256 + threadIdx.x;
  if (i >= n4) return;
  float4 v = ((const float4*)src)[i];
  u16x4 o;
  o[0] = f2bf(v.x); o[1] = f2bf(v.y); o[2] = f2bf(v.z); o[3] = f2bf(v.w);
  *(u16x4*)&dst[i * 4] = o;
}

// permuted-row cast: dst row n' = src row (g*H + jH), n' = jH*4 + g
__global__ void cast_perm(const float* __restrict__ src, int ld, int off,
                          u16* __restrict__ dst) {
  int np = blockIdx.y;
  int c = blockIdx.x * 256 + threadIdx.x;
  int g = np & 3, jH = np >> 2;
  dst[(size_t)np * H + c] = f2bf(src[(size_t)(g * H + jH) * ld + off + c]);
}

__global__ void bias_perm(const float* __restrict__ a,
                          const float* __restrict__ b, float* __restrict__ o) {
  int np = blockIdx.x * 256 + threadIdx.x;
  int g = np & 3, jH = np >> 2;
  int r = g * H + jH;
  o[np] = a[r] + b[r];
}

// dst[c*R + r] = bf16(src[r*ld + off + c]); grid (C/32, R/32)
__global__ __launch_bounds__(256) void cast_transpose_bf(
    const float* __restrict__ src, int ld, int off, u16* __restrict__ dst,
    int R) {
  __shared__ float tile[32][33];
  int r0 = blockIdx.y * 32, c0 = blockIdx.x * 32;
  int tx = threadIdx.x & 31, ty = threadIdx.x >> 5;
#pragma unroll
  for (int i = 0; i < 32; i += 8)
    tile[ty + i][tx] = src[(long)(r0 + ty + i) * ld + off + c0 + tx];
  __syncthreads();
#pragma unroll
  for (int i = 0; i < 32; i += 8)
    dst[(long)(c0 + ty + i) * R + r0 + tx] = f2bf(tile[tx][ty + i]);
}

__global__ void gather_src_emb(const int* __restrict__ src,
                               const float* __restrict__ emb,
                               u16* __restrict__ dst) {
  int row = blockIdx.y;           // row = t*B + b
  int t = row >> 5, b = row & 31;
  int c = blockIdx.x * 256 + threadIdx.x;
  int tok = src[b * S + t];
  dst[(long)row * H + c] = f2bf(emb[(long)tok * H + c]);
}

__global__ void gather_trg_emb(const int* __restrict__ trg,
                               const float* __restrict__ emb,
                               u16* __restrict__ xout) {
  int row = blockIdx.y;           // row = t*B + b, t < 63
  int t = row >> 5, b = row & 31;
  int c = blockIdx.x * 256 + threadIdx.x;
  int tok = trg[b * T + t];
  xout[(long)row * KOUT + 2 * H + c] = f2bf(emb[(long)tok * H + c]);
}

// ---------------- persistent encoder ----------------------------------------
// 128 blocks x 128 threads. Block bk owns cols [bk*4, bk*4+4) for all gates.
// Slot fes[j*16]: value = number of h-steps block j has published.
__global__ __launch_bounds__(128) void enc_persist(
    unsigned* fes, const float* __restrict__ whh,
    const float* __restrict__ xih_p, u16* hstep, u16* enc_bt_bf, float* cbuf) {
  const int tid = threadIdx.x, bk = blockIdx.x;
  const int wave = tid >> 6, lane = tid & 63;
  __shared__ float gs[32][16];
  __shared__ float c_s[128];
  __shared__ u16 hx[128];
  // B-frag preload: lane n=lane&15 -> (g=n&3,q=n>>2); k = kt*32+(lane>>4)*8+e
  bf16x8 wf[16];
  {
    int n = lane & 15, g = n & 3, q = n >> 2;
    const float* wrow =
        whh + ((size_t)g * H + bk * 4 + q) * H + (lane >> 4) * 8;
#pragma unroll
    for (int kt = 0; kt < 16; kt++) {
      bf16x8 f;
#pragma unroll
      for (int e = 0; e < 8; e++) f[e] = (short)f2bf(wrow[kt * 32 + e]);
      wf[kt] = f;
    }
  }
  c_s[tid] = 0.f;
  for (int t = 0; t < S; t++) {
    if (t > 0) {
      poll_slot(fes + tid * 16, (unsigned)t);  // 128 threads x 128 slots
      __syncthreads();
    }
    float4 xv = *(const float4*)(xih_p + ((size_t)t * B + (tid >> 2)) * H4 +
                                 (bk * 4 + (tid & 3)) * 4);
    if (t > 0) {
      const u16* hb = hstep + (size_t)t * B * H +
                      (size_t)(wave * 16 + (lane & 15)) * H + (lane >> 4) * 8;
      f32x4 acc = {};
#pragma unroll
      for (int kt = 0; kt < 16; kt++) {
        bf16x8 a = *(const bf16x8*)(hb + kt * 32);
        acc = __builtin_amdgcn_mfma_f32_16x16x32_bf16(a, wf[kt], acc, 0, 0, 0);
      }
      int n = lane & 15, r0 = (lane >> 4) * 4;
#pragma unroll
      for (int rr = 0; rr < 4; rr++) gs[wave * 16 + r0 + rr][n] = acc[rr];
    } else {
      int n = lane & 15, r0 = (lane >> 4) * 4;
#pragma unroll
      for (int rr = 0; rr < 4; rr++) gs[wave * 16 + r0 + rr][n] = 0.f;
    }
    __syncthreads();
    {
      int b = tid >> 2, q = tid & 3;
      float gi = xv.x + gs[b][q * 4 + 0];
      float gf = xv.y + gs[b][q * 4 + 1];
      float gg = xv.z + gs[b][q * 4 + 2];
      float go = xv.w + gs[b][q * 4 + 3];
      float cn = sigm(gf) * c_s[tid] + sigm(gi) * tanh_(gg);
      c_s[tid] = cn;
      float hn = sigm(go) * tanh_(cn);
      u16 h16 = f2bf(hn);
      hx[tid] = h16;
      enc_bt_bf[((size_t)b * S + t) * H + bk * 4 + q] = h16;  // normal store
    }
    __syncthreads();
    u64 kp = 0;
    if (tid < 32)
      kp = xstore(hstep + (size_t)(t + 1) * B * H + (size_t)tid * H + bk * 4,
                  pack4u(&hx[tid * 4]));
    if (wave == 0) {
      asm volatile("" :: "v"(kp));
      asm volatile("s_waitcnt vmcnt(0)" ::: "memory");
      if (tid == 0) sstore(fes + bk * 16, (unsigned)(t + 1));
    }
  }
  {
    int b = tid >> 2, q = tid & 3;
    cbuf[b * H + bk * 4 + q] = c_s[tid];  // kernel-boundary consumer
  }
}

// ---------------- persistent decoder ----------------------------------------
// 128 blocks x 512 threads.
// fhs[j*16]: # of h publishes by block j (blocks<32 also publish h[0] via fc).
// fws[b*16]: # of weighted publishes by attention block b (b<32).
__global__ __launch_bounds__(512) void dec_persist(
    unsigned* fhs, unsigned* fws, const float* __restrict__ fc_w,
    const float* __restrict__ fc_b, const float* __restrict__ dec_wih,
    const float* __restrict__ dec_whh, const u16* __restrict__ a1T_bf,
    const float* __restrict__ attn_v, const int* __restrict__ src,
    const u16* __restrict__ hf_bf, const float* __restrict__ cbuf,
    const u16* __restrict__ epart_bf, const u16* __restrict__ enc_bt_bf,
    const float* __restrict__ eih_p, u16* hstep, u16* wstep,
    u16* __restrict__ xout_bf) {
  const int tid = threadIdx.x, bk = blockIdx.x;
  const int wave = tid >> 6, lane = tid & 63;
  __shared__ u16 Ws[16 * 1024];     // LSTM weights, XOR-swizzled (32 KB)
  __shared__ float wsum[8][H];      // 16 KB (hp partials / weighted partials)
  __shared__ float hs[H], hps[H];
  __shared__ float gs4[4][32][16];  // 8 KB gate partials
  __shared__ float sc[S], red[2];
  __shared__ int smask[S];
  __shared__ float c_s[128];
  __shared__ u16 hx[128];
  // ---- prologue: LSTM weights -> LDS ----
  for (int idx = tid; idx < 16 * 1024; idx += 512) {
    int n = idx >> 10, k = idx & 1023;
    int g = n & 3, q = n >> 2;
    int grow = g * H + bk * 4 + q;
    float v = (k < 512) ? dec_wih[(size_t)grow * (2 * H) + 512 + k]
                        : dec_whh[(size_t)grow * H + (k - 512)];
    Ws[n * 1024 + (((k >> 3) ^ (n & 7)) << 3) + (k & 7)] = f2bf(v);
  }
  if (tid < 128) c_s[tid] = cbuf[(tid >> 2) * H + bk * 4 + (tid & 3)];
  float av8[8];
  if (bk < 32) {
    if (tid < S) smask[tid] = src[bk * S + tid];
#pragma unroll
    for (int e = 0; e < 8; e++) av8[e] = attn_v[lane * 8 + e];
  }
  // fc: hidden = tanh(hf @ fc_w^T + fc_b) -> h[0]  (blocks 0..31, 16 cols)
  if (bk < 32 && wave < 2) {
    int n = lane & 15;
    const u16* hb = hf_bf + (size_t)(wave * 16 + n) * H + (lane >> 4) * 8;
    const float* frow = fc_w + (size_t)(bk * 16 + n) * H + (lane >> 4) * 8;
    f32x4 acc = {};
#pragma unroll
    for (int kt = 0; kt < 16; kt++) {
      bf16x8 a = *(const bf16x8*)(hb + kt * 32);
      bf16x8 bf;
#pragma unroll
      for (int e = 0; e < 8; e++) bf[e] = (short)f2bf(frow[kt * 32 + e]);
      acc = __builtin_amdgcn_mfma_f32_16x16x32_bf16(a, bf, acc, 0, 0, 0);
    }
    float bias = fc_b[bk * 16 + n];
    int r0 = (lane >> 4) * 4;
#pragma unroll
    for (int rr = 0; rr < 4; rr++)
      gs4[0][wave * 16 + r0 + rr][n] = tanh_(acc[rr] + bias);
  }
  __syncthreads();
  if (bk < 32) {
    u64 kp = 0;
    if (tid < 128) {
      int b = tid >> 2, qq = tid & 3;
      u16 w0 = f2bf(gs4[0][b][qq * 4 + 0]);
      u16 w1 = f2bf(gs4[0][b][qq * 4 + 1]);
      u16 w2 = f2bf(gs4[0][b][qq * 4 + 2]);
      u16 w3 = f2bf(gs4[0][b][qq * 4 + 3]);
      u64 val = (u64)w0 | ((u64)w1 << 16) | ((u64)w2 << 32) | ((u64)w3 << 48);
      kp = xstore(hstep + (size_t)b * H + bk * 16 + qq * 4, val);
    }
    if (wave < 2) {
      asm volatile("" :: "v"(kp));
      asm volatile("s_waitcnt vmcnt(0)" ::: "memory");
    }
    __syncthreads();
    if (tid == 0) sstore(fhs + bk * 16, 1u);
  }
  // ---- time loop ----
  for (int t = 0; t < TD; t++) {
    // wait h[t]: blocks<32 have published t+1 times, others t times
    if (tid < 128)
      poll_slot(fhs + tid * 16, (unsigned)(tid < 32 ? t + 1 : t));
    __syncthreads();
    float4 xv = {};
    if (tid < 128)
      xv = *(const float4*)(eih_p + ((size_t)t * B + (tid >> 2)) * H4 +
                            (bk * 4 + (tid & 3)) * 4);
    // phase 1: attention for batch b = bk (blocks 0..31, all 8 waves)
    if (bk < 32) {
      const int b = bk;
      if (tid < 256) {
        u32 v = ((const u32*)(hstep + (size_t)t * B * H + (size_t)b * H))[tid];
        hs[2 * tid] = bf2f((u16)(v & 0xffff));
        hs[2 * tid + 1] = bf2f((u16)(v >> 16));
      }
      __syncthreads();
      {  // hp partials: wave w covers k in [w*64, w*64+64)
        float p[8] = {};
        const int j0 = lane * 8;
#pragma unroll 4
        for (int kk = 0; kk < 64; kk++) {
          int k = wave * 64 + kk;
          float hk = hs[k];
          u16x8 av = *(const u16x8*)&a1T_bf[(size_t)k * H + j0];
#pragma unroll
          for (int e = 0; e < 8; e++) p[e] += hk * bf2f(av[e]);
        }
#pragma unroll
        for (int e = 0; e < 8; e++) wsum[wave][j0 + e] = p[e];
      }
      __syncthreads();
      {
        float s0 = 0.f;
#pragma unroll
        for (int w = 0; w < 8; w++) s0 += wsum[w][tid];
        hps[tid] = s0;
      }
      __syncthreads();
      {  // scores: wave w covers s in [w*16, w*16+16)
        const int j0 = lane * 8;
        float hp8[8];
#pragma unroll
        for (int e = 0; e < 8; e++) hp8[e] = hps[j0 + e];
        for (int i = 0; i < 16; i++) {
          int s = wave * 16 + i;
          u16x8 ep = *(const u16x8*)&epart_bf[((size_t)b * S + s) * H + j0];
          float a = 0.f;
#pragma unroll
          for (int e = 0; e < 8; e++)
            a += av8[e] * tanhf_(hp8[e] + bf2f(ep[e]));
#pragma unroll
          for (int o = 32; o; o >>= 1) a += __shfl_xor(a, o);
          if (lane == 0) sc[s] = a;
        }
      }
      __syncthreads();
      if (tid < S && smask[tid] == PAD_IDX) sc[tid] = -1e10f;
      __syncthreads();
      if (tid < 64) {
        float v = fmaxf(sc[tid], sc[tid + 64]);
#pragma unroll
        for (int o = 32; o; o >>= 1) v = fmaxf(v, __shfl_xor(v, o));
        if (tid == 0) red[0] = v;
      }
      __syncthreads();
      float mx = red[0];
      if (tid < S) sc[tid] = __expf(sc[tid] - mx);
      __syncthreads();
      if (tid < 64) {
        float v = sc[tid] + sc[tid + 64];
#pragma unroll
        for (int o = 32; o; o >>= 1) v += __shfl_xor(v, o);
        if (tid == 0) red[1] = 1.f / v;
      }
      {  // weighted partials: wave w owns s in [w*16, w*16+16)
        float acc8[8] = {};
        const int j0 = lane * 8;
        for (int i = 0; i < 16; i++) {
          int s = wave * 16 + i;
          float pscale = sc[s];
          u16x8 ev = *(const u16x8*)&enc_bt_bf[((size_t)b * S + s) * H + j0];
#pragma unroll
          for (int e = 0; e < 8; e++) acc8[e] += pscale * bf2f(ev[e]);
        }
#pragma unroll
        for (int e = 0; e < 8; e++) wsum[wave][j0 + e] = acc8[e];
      }
      __syncthreads();
      {  // finalize + publish weighted
        u64 kp = 0;
        if (tid < 128) {
          float inv = red[1];
          int j0 = tid * 4;
          u16x4 o;
#pragma unroll
          for (int i = 0; i < 4; i++) {
            float wj = (wsum[0][j0 + i] + wsum[1][j0 + i] + wsum[2][j0 + i] +
                        wsum[3][j0 + i] + wsum[4][j0 + i] + wsum[5][j0 + i] +
                        wsum[6][j0 + i] + wsum[7][j0 + i]) *
                       inv;
            o[i] = f2bf(wj);
          }
          *(u16x4*)&xout_bf[((size_t)t * B + b) * KOUT + H + j0] = o;
          u64 val = (u64)o[0] | ((u64)o[1] << 16) | ((u64)o[2] << 32) |
                    ((u64)o[3] << 48);
          kp = xstore(wstep + (size_t)t * B * H + (size_t)b * H + j0, val);
        }
        if (wave < 2) {
          asm volatile("" :: "v"(kp));
          asm volatile("s_waitcnt vmcnt(0)" ::: "memory");
        }
        __syncthreads();
        if (tid == 0) sstore(fws + bk * 16, (unsigned)(t + 1));
      }
    }
    // gates_h: waves 0-3 (needs only h[t]); k-split across wave pairs
    if (wave < 4) {
      int p = wave >> 1, sub = wave & 1;
      int m = lane & 15, ks = lane >> 4;
      const u16* hb =
          hstep + (size_t)t * B * H + (size_t)(sub * 16 + m) * H + ks * 8;
      f32x4 acc = {};
#pragma unroll
      for (int kt = p * 8; kt < p * 8 + 8; kt++) {
        bf16x8 a = *(const bf16x8*)(hb + kt * 32);
        bf16x8 w = *(const bf16x8*)&Ws[m * 1024 +
                                       (((64 + kt * 4 + ks) ^ (m & 7)) << 3)];
        acc = __builtin_amdgcn_mfma_f32_16x16x32_bf16(a, w, acc, 0, 0, 0);
      }
      int r0 = ks * 4;
#pragma unroll
      for (int rr = 0; rr < 4; rr++) gs4[p][sub * 16 + r0 + rr][m] = acc[rr];
    }
    // wait weighted[t]
    if (tid < 32) poll_slot(fws + tid * 16, (unsigned)(t + 1));
    __syncthreads();
    // gates_w: waves 4-7; k-split across wave pairs
    if (wave >= 4) {
      int w2 = wave - 4, p = w2 >> 1, sub = w2 & 1;
      int m = lane & 15, ks = lane >> 4;
      const u16* wb_ =
          wstep + (size_t)t * B * H + (size_t)(sub * 16 + m) * H + ks * 8;
      f32x4 acc = {};
#pragma unroll
      for (int kt = p * 8; kt < p * 8 + 8; kt++) {
        bf16x8 a = *(const bf16x8*)(wb_ + kt * 32);
        bf16x8 w =
            *(const bf16x8*)&Ws[m * 1024 + (((kt * 4 + ks) ^ (m & 7)) << 3)];
        acc = __builtin_amdgcn_mfma_f32_16x16x32_bf16(a, w, acc, 0, 0, 0);
      }
      int r0 = ks * 4;
#pragma unroll
      for (int rr = 0; rr < 4; rr++)
        gs4[2 + p][sub * 16 + r0 + rr][m] = acc[rr];
    }
    __syncthreads();
    // pointwise
    if (tid < 128) {
      int b2 = tid >> 2, q = tid & 3;
      float gi = xv.x + gs4[0][b2][q * 4 + 0] + gs4[1][b2][q * 4 + 0] +
                 gs4[2][b2][q * 4 + 0] + gs4[3][b2][q * 4 + 0];
      float gf = xv.y + gs4[0][b2][q * 4 + 1] + gs4[1][b2][q * 4 + 1] +
                 gs4[2][b2][q * 4 + 1] + gs4[3][b2][q * 4 + 1];
      float gg = xv.z + gs4[0][b2][q * 4 + 2] + gs4[1][b2][q * 4 + 2] +
                 gs4[2][b2][q * 4 + 2] + gs4[3][b2][q * 4 + 2];
      float go = xv.w + gs4[0][b2][q * 4 + 3] + gs4[1][b2][q * 4 + 3] +
                 gs4[2][b2][q * 4 + 3] + gs4[3][b2][q * 4 + 3];
      float cn = sigm(gf) * c_s[tid] + sigm(gi) * tanh_(gg);
      c_s[tid] = cn;
      float hn = sigm(go) * tanh_(cn);
      u16 h16 = f2bf(hn);
      hx[tid] = h16;
      xout_bf[((size_t)t * B + b2) * KOUT + bk * 4 + q] = h16;  // normal store
    }
    __syncthreads();
    u64 kp2 = 0;
    if (tid < 32)
      kp2 = xstore(hstep + (size_t)(t + 1) * B * H + (size_t)tid * H + bk * 4,
                   pack4u(&hx[tid * 4]));
    if (wave == 0) {
      asm volatile("" :: "v"(kp2));
      asm volatile("s_waitcnt vmcnt(0)" ::: "memory");
      if (tid == 0)
        sstore(fhs + bk * 16, (unsigned)(bk < 32 ? t + 2 : t + 1));
    }
  }
}

// ---------------------------------------------------------------------------
extern "C" void kernel_launch(void* const* d_in, const int* in_sizes, int n_in,
                              void* d_out, int out_size, void* d_ws,
                              size_t ws_size, hipStream_t stream) {
  const int* src = (const int*)d_in[0];
  const int* trg = (const int*)d_in[2];
  const float* enc_emb = (const float*)d_in[3];
  const float* enc_wih = (const float*)d_in[4];
  const float* enc_whh = (const float*)d_in[5];
  const float* enc_bih = (const float*)d_in[6];
  const float* enc_bhh = (const float*)d_in[7];
  const float* fc_w = (const float*)d_in[8];
  const float* fc_b = (const float*)d_in[9];
  const float* dec_emb = (const float*)d_in[10];
  const float* attn_w = (const float*)d_in[11];
  const float* attn_b = (const float*)d_in[12];
  const float* attn_v = (const float*)d_in[13];
  const float* dec_wih = (const float*)d_in[14];
  const float* dec_whh = (const float*)d_in[15];
  const float* dec_bih = (const float*)d_in[16];
  const float* dec_bhh = (const float*)d_in[17];
  const float* out_w = (const float*)d_in[18];
  const float* out_b = (const float*)d_in[19];
  float* out = (float*)d_out;

  char* wp = (char*)d_ws;
  auto alloc = [&](size_t n) {
    char* p = wp;
    wp += (n + 255) & ~(size_t)255;
    return p;
  };
  u16* outw_bf = (u16*)alloc((size_t)V * KOUT * 2);        // 98.3 MB
  u16* wihenc_p = (u16*)alloc((size_t)H4 * H * 2);         // 2.1 MB
  u16* wihE_p = (u16*)alloc((size_t)H4 * H * 2);           // 2.1 MB
  u16* attnw2_bf = (u16*)alloc((size_t)H * H * 2);         // 0.5 MB
  u16* a1T_bf = (u16*)alloc((size_t)H * H * 2);            // 0.5 MB
  u16* xemb_bf = (u16*)alloc((size_t)S * B * H * 2);       // 4.2 MB
  float* xih_p = (float*)alloc((size_t)S * B * H4 * 4);    // 33.6 MB
  u16* enc_bt_bf = (u16*)alloc((size_t)B * S * H * 2);     // 4.2 MB
  u16* epart_bf = (u16*)alloc((size_t)B * S * H * 2);      // 4.2 MB
  float* eih_p = (float*)alloc((size_t)MOUT * H4 * 4);     // 16.5 MB
  u16* xout_bf = (u16*)alloc((size_t)MOUT * KOUT * 2);     // 6.2 MB
  u16* hstep_enc = (u16*)alloc((size_t)(S + 1) * B * H * 2);  // 4.3 MB
  u16* hstep_dec = (u16*)alloc((size_t)T * B * H * 2);        // 2.1 MB
  u16* wstep = (u16*)alloc((size_t)TD * B * H * 2);           // 2.1 MB
  float* cbuf = (float*)alloc((size_t)B * H * 4);
  float* benc_p = (float*)alloc((size_t)H4 * 4);
  float* bdec_p = (float*)alloc((size_t)H4 * 4);
  unsigned* flags = (unsigned*)alloc(4608 * 4);
  unsigned* fes = flags;            // 128 slots x 16 u32
  unsigned* fhs = flags + 2048;     // 128 slots x 16 u32
  unsigned* fws = flags + 4096;     // 32 slots x 16 u32

  dim3 blk(256);
  zero_f<<<dim3(256), blk, 0, stream>>>(out, (long)B * V);
  zero_u<<<dim3(18), blk, 0, stream>>>(flags, 4608);
  // weight preparation
  cast_bf4<<<dim3(((long)V * KOUT / 4 + 255) / 256), blk, 0, stream>>>(
      out_w, outw_bf, (long)V * KOUT / 4);
  cast_perm<<<dim3(H / 256, H4), blk, 0, stream>>>(enc_wih, H, 0, wihenc_p);
  cast_perm<<<dim3(H / 256, H4), blk, 0, stream>>>(dec_wih, 2 * H, 0, wihE_p);
  cast_bf<<<dim3(H / 256, H), blk, 0, stream>>>(attn_w, attnw2_bf, 2 * H, H, H);
  cast_transpose_bf<<<dim3(H / 32, H / 32), blk, 0, stream>>>(attn_w, 2 * H, 0,
                                                              a1T_bf, H);
  bias_perm<<<dim3(H4 / 256), blk, 0, stream>>>(enc_bih, enc_bhh, benc_p);
  bias_perm<<<dim3(H4 / 256), blk, 0, stream>>>(dec_bih, dec_bhh, bdec_p);
  gather_src_emb<<<dim3(H / 256, S * B), blk, 0, stream>>>(src, enc_emb,
                                                           xemb_bf);
  gather_trg_emb<<<dim3(H / 256, MOUT), blk, 0, stream>>>(trg, dec_emb,
                                                          xout_bf);
  // input-side GEMMs (permuted cols)
  gemm_bt<<<dim3(H4 / 128, (S * B) / 128), blk, 0, stream>>>(
      xemb_bf, H, wihenc_p, H, xih_p, H4, benc_p, S * B, H, 0);
  gemm_bt<<<dim3(H4 / 128, (MOUT + 127) / 128), blk, 0, stream>>>(
      xout_bf + 2 * H, KOUT, wihE_p, H, eih_p, H4, bdec_p, MOUT, H, 0);
  // persistent encoder
  enc_persist<<<dim3(128), dim3(128), 0, stream>>>(fes, enc_whh, xih_p,
                                                   hstep_enc, enc_bt_bf, cbuf);
  // epart = enc_bt @ attn_w2^T + attn_b  (bf16 out)
  gemm_bt<<<dim3(H / 128, (B * S) / 128), blk, 0, stream>>>(
      enc_bt_bf, H, attnw2_bf, H, (float*)epart_bf, H, attn_b, B * S, H, 1);
  // persistent decoder (h_f = hstep_enc step S)
  dec_persist<<<dim3(128), dim3(512), 0, stream>>>(
      fhs, fws, fc_w, fc_b, dec_wih, dec_whh, a1T_bf, attn_v, src,
      hstep_enc + (size_t)S * B * H, cbuf, epart_bf, enc_bt_bf, eih_p,
      hstep_dec, wstep, xout_bf);
  // final logits GEMM
  gemm_bt<<<dim3(V / 128, (MOUT + 127) / 128), blk, 0, stream>>>(
      xout_bf, KOUT, outw_bf, KOUT, out + (size_t)B * V, V, out_b, MOUT, KOUT,
      0);
}